// Round 2
// baseline (1161.761 us; speedup 1.0000x reference)
//
#include <hip/hip_runtime.h>
#include <stdint.h>

using u16 = unsigned short;

#define DEVI static __device__ __forceinline__

constexpr int BATCH  = 2;
constexpr int NPTS   = 50000;
constexpr int TOTPTS = BATCH * NPTS;      // 100000
constexpr int CIMG   = 256;
constexpr int MIDC   = 128;
constexpr int OUTC   = 128;
constexpr int PTSC   = 64;
constexpr int KIMG   = 384;               // 3 * 128
constexpr int KTOT   = 448;               // 384 + 64
constexpr float WPADf = 1280.f, HPADf = 384.f;
constexpr float BNEPS = 1e-3f;

DEVI u16 f2bf(float f) {                  // RNE float -> bf16 bits
  unsigned x = __float_as_uint(f);
  return (u16)((x + 0x7fffu + ((x >> 16) & 1u)) >> 16);
}
DEVI float bf2f(u16 u) { return __uint_as_float(((unsigned)u) << 16); }

// ---------------- prep: fold BN into weights/bias, k-major transpose -------
__global__ __launch_bounds__(256) void prep_kernel(
    const float* __restrict__ img_w, const float* __restrict__ img_b,
    const float* __restrict__ ig, const float* __restrict__ ibb,
    const float* __restrict__ im, const float* __restrict__ iv,
    const float* __restrict__ pts_w, const float* __restrict__ pts_b,
    const float* __restrict__ pg, const float* __restrict__ pbb,
    const float* __restrict__ pm, const float* __restrict__ pv,
    float* __restrict__ wT, float* __restrict__ bias)
{
  int e = blockIdx.x * 256 + threadIdx.x;
  if (e >= KTOT * OUTC) return;
  int o = e & (OUTC - 1);
  int k = e >> 7;
  float s1 = ig[o] * rsqrtf(iv[o] + BNEPS);
  float s2 = pg[o] * rsqrtf(pv[o] + BNEPS);
  if (e < OUTC)
    bias[o] = (img_b[o] - im[o]) * s1 + ibb[o] +
              (pts_b[o] - pm[o]) * s2 + pbb[o];
  wT[e] = (k < KIMG) ? img_w[o * KIMG + k] * s1
                     : pts_w[o * PTSC + (k - KIMG)] * s2;
}

// ---------------- conv 3x3 SAME, 256->128, fp32 compute, bf16 NHWC out -----
// Block: 256 threads = 4 waves. Each wave owns 16 output channels
// (broadcast weight reads), each lane owns 2 pixels of a TH*TW=128 tile.
template<int TH, int TW>
__global__ __launch_bounds__(256) void conv_kernel(
    const float* __restrict__ in,     // [B][256][H][W]
    const float* __restrict__ wsrc,   // [128][256][3][3] (level slice)
    const float* __restrict__ bsrc,   // [128]
    u16* __restrict__ out,            // [B][H][W][128] bf16
    int H, int W, int tiles_x)
{
  constexpr int INW = TW + 2, INH = TH + 2, INHW = INW * INH;
  constexpr int ICT = 8;
  constexpr int DY  = 64 / TW;        // row offset of each lane's 2nd pixel
  __shared__ float s_in[ICT * INHW];
  __shared__ float s_w[ICT * 9 * 64]; // [(ici*9+tap)][oc 0..63]

  const int t    = threadIdx.x;
  const int lane = t & 63;
  const int g    = t >> 6;            // wave id -> oc sub-group (16 ocs)
  const int b    = blockIdx.y;
  const int half = blockIdx.z;        // oc half (0/1)
  const int tx   = blockIdx.x % tiles_x, ty = blockIdx.x / tiles_x;
  const int x0   = tx * TW, y0 = ty * TH;
  const int px   = lane % TW, py = lane / TW;

  float acc0[16], acc1[16];
  #pragma unroll
  for (int o = 0; o < 16; ++o) { acc0[o] = 0.f; acc1[o] = 0.f; }

  const float* wbase = wsrc + (size_t)(half * 64) * (CIMG * 9);

  for (int ic0 = 0; ic0 < CIMG; ic0 += ICT) {
    __syncthreads();
    for (int e = t; e < ICT * INHW; e += 256) {
      int ici = e / INHW, r = e % INHW;
      int yy = y0 + (r / INW) - 1;
      int xx = x0 + (r % INW) - 1;
      float v = 0.f;
      if (yy >= 0 && yy < H && xx >= 0 && xx < W)
        v = in[((size_t)(b * CIMG + ic0 + ici) * H + yy) * W + xx];
      s_in[e] = v;
    }
    for (int e = t; e < ICT * 9 * 64; e += 256) {
      int oc = e / 72, kt = e % 72;   // kt = ici*9+tap, contiguous in global
      s_w[kt * 64 + oc] = wbase[(size_t)oc * (CIMG * 9) + ic0 * 9 + kt];
    }
    __syncthreads();
    #pragma unroll 2
    for (int ici = 0; ici < ICT; ++ici) {
      #pragma unroll
      for (int ky = 0; ky < 3; ++ky) {
        #pragma unroll
        for (int kx = 0; kx < 3; ++kx) {
          const float v0 = s_in[ici * INHW + (py + ky) * INW + (px + kx)];
          const float v1 = s_in[ici * INHW + (py + DY + ky) * INW + (px + kx)];
          const float* wp = s_w + (ici * 9 + ky * 3 + kx) * 64 + g * 16;
          float wv[16];
          *(float4*)&wv[0]  = *(const float4*)(wp);
          *(float4*)&wv[4]  = *(const float4*)(wp + 4);
          *(float4*)&wv[8]  = *(const float4*)(wp + 8);
          *(float4*)&wv[12] = *(const float4*)(wp + 12);
          #pragma unroll
          for (int o = 0; o < 16; ++o) {
            acc0[o] += v0 * wv[o];
            acc1[o] += v1 * wv[o];
          }
        }
      }
    }
  }

  const int ocb = half * 64 + g * 16;
  float bv[16];
  #pragma unroll
  for (int o = 0; o < 16; ++o) bv[o] = bsrc[ocb + o];
  #pragma unroll
  for (int pi = 0; pi < 2; ++pi) {
    int yy = y0 + py + pi * DY;
    int xx = x0 + px;
    if (yy < H && xx < W) {
      u16* po = out + ((size_t)(b * H + yy) * W + xx) * MIDC + ocb;
      const float* a = pi ? acc1 : acc0;
      u16 tmp[16];
      #pragma unroll
      for (int o = 0; o < 16; ++o) tmp[o] = f2bf(a[o] + bv[o]);
      #pragma unroll
      for (int q = 0; q < 4; ++q)
        *(ushort4*)(po + q * 4) = *(const ushort4*)(tmp + q * 4);
    }
  }
}

// ---------------- projection + bilinear sampling -> img_pts bf16 ----------
DEVI float tap(const u16* __restrict__ f, int Hl, int Wl, int b,
               float xf, float yf, int c, float w) {
  if (xf < 0.f || xf > (float)(Wl - 1) || yf < 0.f || yf > (float)(Hl - 1))
    return 0.f;
  int xi = (int)xf, yi = (int)yf;
  return w * bf2f(f[((size_t)(b * Hl + yi) * Wl + xi) * MIDC + c]);
}

__global__ __launch_bounds__(256) void sample_kernel(
    const float* __restrict__ pts, const float* __restrict__ l2i,
    const float* __restrict__ rot, const float* __restrict__ trans,
    const u16* __restrict__ f0, const u16* __restrict__ f1,
    const u16* __restrict__ f2, u16* __restrict__ img_pts)
{
  const int t  = threadIdx.x;
  const int c  = t & 127;
  const int pt = blockIdx.x * 2 + (t >> 7);
  const int b  = pt / NPTS;

  const float* P = pts + (size_t)pt * 3;
  const float* T = trans + b * 3;
  const float* R = rot + b * 9;
  const float* L = l2i + b * 16;
  float dx = P[0] - T[0], dy = P[1] - T[1], dz = P[2] - T[2];
  // p = (pts - tr) @ inv(R) = (pts - tr) @ R^T  ->  p_j = sum_i d_i R[j][i]
  float p0 = dx * R[0] + dy * R[1] + dz * R[2];
  float p1 = dx * R[3] + dy * R[4] + dz * R[5];
  float p2 = dx * R[6] + dy * R[7] + dz * R[8];
  float pc0 = L[0] * p0 + L[1] * p1 + L[2]  * p2 + L[3];
  float pc1 = L[4] * p0 + L[5] * p1 + L[6]  * p2 + L[7];
  float pc2 = L[8] * p0 + L[9] * p1 + L[10] * p2 + L[11];
  float z  = fmaxf(pc2, 1e-5f);
  float gx = pc0 / z / WPADf * 2.f - 1.f;
  float gy = pc1 / z / HPADf * 2.f - 1.f;

  const u16* feats[3] = {f0, f1, f2};
  const int Hs[3] = {48, 24, 12}, Ws[3] = {160, 80, 40};
  u16* orow = img_pts + (size_t)pt * KIMG;
  #pragma unroll
  for (int l = 0; l < 3; ++l) {
    const int Hl = Hs[l], Wl = Ws[l];
    float ix = (gx + 1.f) * 0.5f * (float)(Wl - 1);
    float iy = (gy + 1.f) * 0.5f * (float)(Hl - 1);
    float xf0 = floorf(ix), yf0 = floorf(iy);
    float wx1 = ix - xf0, wy1 = iy - yf0;
    float wx0 = 1.f - wx1, wy0 = 1.f - wy1;
    float v = tap(feats[l], Hl, Wl, b, xf0,       yf0,       c, wx0 * wy0)
            + tap(feats[l], Hl, Wl, b, xf0 + 1.f, yf0,       c, wx1 * wy0)
            + tap(feats[l], Hl, Wl, b, xf0,       yf0 + 1.f, c, wx0 * wy1)
            + tap(feats[l], Hl, Wl, b, xf0 + 1.f, yf0 + 1.f, c, wx1 * wy1);
    orow[l * MIDC + c] = f2bf(v);
  }
}

// ---------------- fused GEMM (img 384 + pts 64) + bias + relu --------------
__global__ __launch_bounds__(256) void gemm_kernel(
    const u16*  __restrict__ Aimg,   // [100000][384] bf16
    const float* __restrict__ Apts,  // [100000][64]  fp32
    const float* __restrict__ wT,    // [448][128] fused, k-major
    const float* __restrict__ bias,  // [128]
    float* __restrict__ outp)        // [100000][128]
{
  __shared__ float sA[64][68];       // [k][row], stride 68 keeps b128 aligned
  __shared__ float sW[64][128];
  const int t    = threadIdx.x;
  const int row0 = blockIdx.x * 64;
  const int rb   = (t & 15) * 4;     // 4 rows per thread
  const int cb   = (t >> 4) * 8;     // 8 cols per thread
  float acc[4][8];
  #pragma unroll
  for (int i = 0; i < 4; ++i)
    #pragma unroll
    for (int j = 0; j < 8; ++j) acc[i][j] = 0.f;

  const int r_st  = t >> 2;          // staging row (0..63)
  const int ks    = (t & 3) * 16;    // staging k offset
  const int arow  = row0 + r_st;
  const bool rv   = arow < TOTPTS;

  for (int k0 = 0; k0 < KTOT; k0 += 64) {
    __syncthreads();
    float tv[16];
    if (!rv) {
      #pragma unroll
      for (int i = 0; i < 16; ++i) tv[i] = 0.f;
    } else if (k0 < KIMG) {
      const u16* src = Aimg + (size_t)arow * KIMG + k0 + ks;
      uint4 q0 = *(const uint4*)(src);
      uint4 q1 = *(const uint4*)(src + 8);
      const u16* a = (const u16*)&q0;
      const u16* bq = (const u16*)&q1;
      #pragma unroll
      for (int i = 0; i < 8; ++i) { tv[i] = bf2f(a[i]); tv[8 + i] = bf2f(bq[i]); }
    } else {
      const float* src = Apts + (size_t)arow * PTSC + ks;
      #pragma unroll
      for (int i = 0; i < 4; ++i) {
        float4 v = *(const float4*)(src + i * 4);
        tv[i*4] = v.x; tv[i*4+1] = v.y; tv[i*4+2] = v.z; tv[i*4+3] = v.w;
      }
    }
    #pragma unroll
    for (int i = 0; i < 16; ++i) sA[ks + i][r_st] = tv[i];

    #pragma unroll
    for (int i = 0; i < 8; ++i) {
      int fidx = t + i * 256;
      int kk = fidx >> 5;
      int oc4 = (fidx & 31) << 2;
      *(float4*)&sW[kk][oc4] = *(const float4*)&wT[(size_t)(k0 + kk) * OUTC + oc4];
    }
    __syncthreads();

    #pragma unroll 8
    for (int kk = 0; kk < 64; ++kk) {
      float4 a  = *(const float4*)&sA[kk][rb];
      float4 w0 = *(const float4*)&sW[kk][cb];
      float4 w1 = *(const float4*)&sW[kk][cb + 4];
      float av[4] = {a.x, a.y, a.z, a.w};
      float wv[8] = {w0.x, w0.y, w0.z, w0.w, w1.x, w1.y, w1.z, w1.w};
      #pragma unroll
      for (int i = 0; i < 4; ++i)
        #pragma unroll
        for (int j = 0; j < 8; ++j) acc[i][j] += av[i] * wv[j];
    }
  }

  float bv[8];
  #pragma unroll
  for (int j = 0; j < 8; ++j) bv[j] = bias[cb + j];
  #pragma unroll
  for (int i = 0; i < 4; ++i) {
    int row = row0 + rb + i;
    if (row < TOTPTS) {
      float4 o0, o1;
      o0.x = fmaxf(acc[i][0] + bv[0], 0.f);
      o0.y = fmaxf(acc[i][1] + bv[1], 0.f);
      o0.z = fmaxf(acc[i][2] + bv[2], 0.f);
      o0.w = fmaxf(acc[i][3] + bv[3], 0.f);
      o1.x = fmaxf(acc[i][4] + bv[4], 0.f);
      o1.y = fmaxf(acc[i][5] + bv[5], 0.f);
      o1.z = fmaxf(acc[i][6] + bv[6], 0.f);
      o1.w = fmaxf(acc[i][7] + bv[7], 0.f);
      float* po = outp + (size_t)row * OUTC + cb;
      *(float4*)(po)     = o0;
      *(float4*)(po + 4) = o1;
    }
  }
}

// ---------------- host ------------------------------------------------------
extern "C" void kernel_launch(void* const* d_in, const int* in_sizes, int n_in,
                              void* d_out, int out_size, void* d_ws, size_t ws_size,
                              hipStream_t stream) {
  // Inputs in setup_inputs() DICT ORDER (not the reference fn signature!):
  //  0..2 img_feats, 3 pts, 4 pts_feats, 5 lidar2img, 6 pcd_rotation,
  //  7 pcd_trans, 8 lat_w, 9 lat_b, 10 img_w, 11 img_b,
  //  12 pts_w, 13 pts_b, 14..17 img_bn_{g,b,m,v}, 18..21 pts_bn_{g,b,m,v}
  const float* f0_in  = (const float*)d_in[0];   // [2][256][48][160]
  const float* f1_in  = (const float*)d_in[1];   // [2][256][24][80]
  const float* f2_in  = (const float*)d_in[2];   // [2][256][12][40]
  const float* pts    = (const float*)d_in[3];   // [2][50000][3]
  const float* ptsf   = (const float*)d_in[4];   // [100000][64]
  const float* l2i    = (const float*)d_in[5];   // [2][4][4]
  const float* rot    = (const float*)d_in[6];   // [2][3][3]
  const float* trans  = (const float*)d_in[7];   // [2][3]
  const float* lat_w  = (const float*)d_in[8];   // [3][128][256][3][3]
  const float* lat_b  = (const float*)d_in[9];   // [3][128]
  const float* img_w  = (const float*)d_in[10];  // [128][384]
  const float* img_b  = (const float*)d_in[11];  // [128]
  const float* pts_w  = (const float*)d_in[12];  // [128][64]
  const float* pts_b  = (const float*)d_in[13];  // [128]
  const float* ibg    = (const float*)d_in[14];  // img_bn_g
  const float* ibbv   = (const float*)d_in[15];  // img_bn_b
  const float* ibm    = (const float*)d_in[16];  // img_bn_m
  const float* ibv    = (const float*)d_in[17];  // img_bn_v
  const float* pbg    = (const float*)d_in[18];  // pts_bn_g
  const float* pbbv   = (const float*)d_in[19];  // pts_bn_b
  const float* pbm    = (const float*)d_in[20];  // pts_bn_m
  const float* pbv    = (const float*)d_in[21];  // pts_bn_v
  float* outp = (float*)d_out;

  uint8_t* ws = (uint8_t*)d_ws;
  // ws layout (256B-aligned)
  const size_t off_c0   = 0;                         // 2*48*160*128 bf16
  const size_t off_c1   = 3932160;                   // 2*24*80*128 bf16
  const size_t off_c2   = off_c1 + 983040;           // 2*12*40*128 bf16
  const size_t off_wT   = off_c2 + 245760;           // 448*128 f32
  const size_t off_bias = off_wT + KTOT * OUTC * 4;  // 128 f32
  const size_t off_imgp = off_bias + 512;            // 100000*384 bf16

  u16*   c0   = (u16*)(ws + off_c0);
  u16*   c1   = (u16*)(ws + off_c1);
  u16*   c2   = (u16*)(ws + off_c2);
  float* wT   = (float*)(ws + off_wT);
  float* bias = (float*)(ws + off_bias);
  u16*   imgp = (u16*)(ws + off_imgp);

  prep_kernel<<<(KTOT * OUTC + 255) / 256, 256, 0, stream>>>(
      img_w, img_b, ibg, ibbv, ibm, ibv,
      pts_w, pts_b, pbg, pbbv, pbm, pbv, wT, bias);

  const size_t WSTRIDE = (size_t)MIDC * CIMG * 9;    // 294912 per level
  conv_kernel<8, 16><<<dim3(60, BATCH, 2), 256, 0, stream>>>(
      f0_in, lat_w,               lat_b,       c0, 48, 160, 10);
  conv_kernel<8, 16><<<dim3(15, BATCH, 2), 256, 0, stream>>>(
      f1_in, lat_w + WSTRIDE,     lat_b + 128, c1, 24, 80, 5);
  conv_kernel<16, 8><<<dim3(5, BATCH, 2), 256, 0, stream>>>(
      f2_in, lat_w + 2 * WSTRIDE, lat_b + 256, c2, 12, 40, 5);

  sample_kernel<<<TOTPTS / 2, 256, 0, stream>>>(
      pts, l2i, rot, trans, c0, c1, c2, imgp);

  gemm_kernel<<<(TOTPTS + 63) / 64, 256, 0, stream>>>(
      imgp, ptsf, wT, bias, outp);

  (void)in_sizes; (void)n_in; (void)out_size; (void)ws_size;
}

// Round 3
// 261.431 us; speedup vs baseline: 4.4439x; 4.4439x over previous
//
#include <hip/hip_runtime.h>
#include <stdint.h>

using u16 = unsigned short;
typedef __attribute__((ext_vector_type(8))) short bf16x8;
typedef __attribute__((ext_vector_type(4))) float f32x4;

#define DEVI static __device__ __forceinline__

constexpr int BATCH  = 2;
constexpr int NPTS   = 50000;
constexpr int TOTPTS = BATCH * NPTS;      // 100000
constexpr int CIMG   = 256;
constexpr int MIDC   = 128;
constexpr int OUTC   = 128;
constexpr int PTSC   = 64;
constexpr int KIMG   = 384;               // 3 * 128
constexpr int KTOT   = 448;
constexpr float WPADf = 1280.f, HPADf = 384.f;
constexpr float BNEPS = 1e-3f;

DEVI u16 f2bf(float f) {                  // RNE float -> bf16 bits
  unsigned x = __float_as_uint(f);
  return (u16)((x + 0x7fffu + ((x >> 16) & 1u)) >> 16);
}
DEVI float bf2f(u16 u) { return __uint_as_float(((unsigned)u) << 16); }

// ============================ zero padded bufs =============================
__global__ __launch_bounds__(256) void zero_kernel(uint4* __restrict__ p, int n16) {
  int i = blockIdx.x * 256 + threadIdx.x;
  int stride = gridDim.x * 256;
  for (; i < n16; i += stride) p[i] = uint4{0u, 0u, 0u, 0u};
}

// ================= NCHW fp32 -> padded NHWC bf16 (per level) ===============
__global__ __launch_bounds__(256) void nchw2nhwc_kernel(
    const float* __restrict__ in, u16* __restrict__ outp, int H, int W) {
  __shared__ float s[64][33];
  const int t  = threadIdx.x;
  const int x0 = blockIdx.x * 32;
  const int y  = blockIdx.y;
  const int b  = blockIdx.z >> 2;
  const int c0 = (blockIdx.z & 3) * 64;
  #pragma unroll
  for (int i = 0; i < 8; ++i) {
    int e = t + i * 256, ci = e >> 5, xi = e & 31;
    float v = 0.f;
    if (x0 + xi < W) v = in[((size_t)(b * CIMG + c0 + ci) * H + y) * W + x0 + xi];
    s[ci][xi] = v;
  }
  __syncthreads();
  const int Wp = W + 2;
  #pragma unroll
  for (int i = 0; i < 8; ++i) {
    int e = t + i * 256, xi = e >> 6, ci = e & 63;
    if (x0 + xi < W)
      outp[((size_t)(b * (H + 2) + y + 1) * Wp + x0 + xi + 1) * CIMG + c0 + ci] =
          f2bf(s[ci][xi]);
  }
}

// ====== prep: BN-fold + bf16 frag-pack of GEMM & conv weights + bias =======
// pack layout: [ks][col(128)][s(4)][j(8)]  (k = ks*32 + s*8 + j)
__global__ __launch_bounds__(256) void prep_kernel(
    const float* __restrict__ img_w, const float* __restrict__ img_b,
    const float* __restrict__ pts_w, const float* __restrict__ pts_b,
    const float* __restrict__ ibg, const float* __restrict__ ibb,
    const float* __restrict__ ibm, const float* __restrict__ ibv,
    const float* __restrict__ pbg, const float* __restrict__ pbb,
    const float* __restrict__ pbm, const float* __restrict__ pbv,
    const float* __restrict__ lat_w,
    u16* __restrict__ wg, u16* __restrict__ wc, float* __restrict__ bias)
{
  int e = blockIdx.x * 256 + threadIdx.x;
  if (e < 57344) {                                   // GEMM pack 14*128*32
    int j = e & 7, s = (e >> 3) & 3, c = (e >> 5) & 127, ks = e >> 12;
    int k = ks * 32 + s * 8 + j;
    float s1 = ibg[c] * rsqrtf(ibv[c] + BNEPS);
    float s2 = pbg[c] * rsqrtf(pbv[c] + BNEPS);
    float w = (k < KIMG) ? img_w[c * KIMG + k] * s1
                         : pts_w[c * PTSC + (k - KIMG)] * s2;
    wg[e] = f2bf(w);
    if (e < OUTC) {
      float t1 = ibg[e] * rsqrtf(ibv[e] + BNEPS);
      float t2 = pbg[e] * rsqrtf(pbv[e] + BNEPS);
      bias[e] = (img_b[e] - ibm[e]) * t1 + ibb[e] +
                (pts_b[e] - pbm[e]) * t2 + pbb[e];
    }
  } else if (e < 57344 + 3 * 294912) {               // conv pack 3*72*128*32
    int q = e - 57344;
    int l = q / 294912, r = q % 294912;
    int j = r & 7, s = (r >> 3) & 3, c = (r >> 5) & 127, ks = r >> 12;
    int k = ks * 32 + s * 8 + j;                     // 0..2303
    int tap = k >> 8, ic = k & 255;
    float w = lat_w[(((size_t)l * 128 + c) * 256 + ic) * 9 + tap];
    wc[(size_t)l * 294912 + r] = f2bf(w);
  }
}

// =================== conv as implicit-GEMM MFMA (all levels) ===============
struct ConvParams {
  int base[4];          // block-id level boundaries
  int H[3], W[3], tx[3];
  int poff[3];          // padded-input offsets (elements)
  int coff[3];          // conv-out offsets (elements)
  int woff[3];          // weight-pack offsets (elements)
};

__global__ __launch_bounds__(256) void conv_mfma_kernel(
    const u16* __restrict__ pad, const u16* __restrict__ wc,
    const float* __restrict__ lat_b, u16* __restrict__ outbuf, ConvParams P)
{
  const int bid = blockIdx.x;
  const int lvl = (bid >= P.base[1]) + (bid >= P.base[2]);
  const int local = bid - P.base[lvl];
  const int H = P.H[lvl], W = P.W[lvl], tilesx = P.tx[lvl];
  const int nxy = tilesx * (H >> 2);
  const int b = local / nxy;
  const int r = local % nxy;
  const int ty = r / tilesx, tx = r % tilesx;
  const int y0 = ty * 4, x0 = tx * 16;
  const u16* __restrict__ pin = pad + P.poff[lvl];
  const u16* __restrict__ wl  = wc + P.woff[lvl];
  u16* __restrict__ outp = outbuf + P.coff[lvl];

  const int t = threadIdx.x, l = t & 63, wv = t >> 6;
  const int wm = wv >> 1, wn = wv & 1;
  const int lr = l & 15, lk = l >> 4;
  const int Wp = W + 2;

  f32x4 acc[2][4] = {};

  size_t abase[2];
  #pragma unroll
  for (int ag = 0; ag < 2; ++ag)
    abase[ag] = (((size_t)(b * (H + 2) + y0 + wm * 2 + ag) * Wp) + x0 + lr) * CIMG + lk * 8;
  const u16* __restrict__ bln = wl + ((wn * 64 + lr) * 4 + lk) * 8;  // lane base

  for (int tap = 0; tap < 9; ++tap) {
    const int ky = tap / 3, kx = tap - ky * 3;
    const size_t toff = ((size_t)ky * Wp + kx) * CIMG;
    const u16* __restrict__ a0 = pin + abase[0] + toff;
    const u16* __restrict__ a1 = pin + abase[1] + toff;
    const u16* __restrict__ bt = bln + (size_t)tap * 8 * 4096;  // ks stride 4096 elems
    #pragma unroll
    for (int icc = 0; icc < 8; ++icc) {
      bf16x8 A0 = *(const bf16x8*)(a0 + icc * 32);
      bf16x8 A1 = *(const bf16x8*)(a1 + icc * 32);
      bf16x8 B0 = *(const bf16x8*)(bt + icc * 4096);
      bf16x8 B1 = *(const bf16x8*)(bt + icc * 4096 + 512);
      bf16x8 B2 = *(const bf16x8*)(bt + icc * 4096 + 1024);
      bf16x8 B3 = *(const bf16x8*)(bt + icc * 4096 + 1536);
      acc[0][0] = __builtin_amdgcn_mfma_f32_16x16x32_bf16(A0, B0, acc[0][0], 0, 0, 0);
      acc[0][1] = __builtin_amdgcn_mfma_f32_16x16x32_bf16(A0, B1, acc[0][1], 0, 0, 0);
      acc[0][2] = __builtin_amdgcn_mfma_f32_16x16x32_bf16(A0, B2, acc[0][2], 0, 0, 0);
      acc[0][3] = __builtin_amdgcn_mfma_f32_16x16x32_bf16(A0, B3, acc[0][3], 0, 0, 0);
      acc[1][0] = __builtin_amdgcn_mfma_f32_16x16x32_bf16(A1, B0, acc[1][0], 0, 0, 0);
      acc[1][1] = __builtin_amdgcn_mfma_f32_16x16x32_bf16(A1, B1, acc[1][1], 0, 0, 0);
      acc[1][2] = __builtin_amdgcn_mfma_f32_16x16x32_bf16(A1, B2, acc[1][2], 0, 0, 0);
      acc[1][3] = __builtin_amdgcn_mfma_f32_16x16x32_bf16(A1, B3, acc[1][3], 0, 0, 0);
    }
  }

  const int ocb = wn * 64;
  #pragma unroll
  for (int ag = 0; ag < 2; ++ag) {
    const int y = y0 + wm * 2 + ag;
    #pragma unroll
    for (int rr = 0; rr < 4; ++rr) {
      const int x = x0 + lk * 4 + rr;
      if (x < W) {
        const size_t o = ((size_t)(b * H + y) * W + x) * MIDC;
        #pragma unroll
        for (int nf = 0; nf < 4; ++nf) {
          const int oc = ocb + nf * 16 + lr;
          outp[o + oc] = f2bf(acc[ag][nf][rr] + lat_b[lvl * 128 + oc]);
        }
      }
    }
  }
}

// ================= projection + bilinear sampling -> img_pts ===============
DEVI float tap(const u16* __restrict__ f, int Hl, int Wl, int b,
               float xf, float yf, int c, float w) {
  if (xf < 0.f || xf > (float)(Wl - 1) || yf < 0.f || yf > (float)(Hl - 1))
    return 0.f;
  int xi = (int)xf, yi = (int)yf;
  return w * bf2f(f[((size_t)(b * Hl + yi) * Wl + xi) * MIDC + c]);
}

__global__ __launch_bounds__(256) void sample_kernel(
    const float* __restrict__ pts, const float* __restrict__ l2i,
    const float* __restrict__ rot, const float* __restrict__ trans,
    const u16* __restrict__ f0, const u16* __restrict__ f1,
    const u16* __restrict__ f2, u16* __restrict__ img_pts)
{
  const int t  = threadIdx.x;
  const int c  = t & 127;
  const int pt = blockIdx.x * 2 + (t >> 7);
  const int b  = pt / NPTS;

  const float* P = pts + (size_t)pt * 3;
  const float* T = trans + b * 3;
  const float* R = rot + b * 9;
  const float* L = l2i + b * 16;
  float dx = P[0] - T[0], dy = P[1] - T[1], dz = P[2] - T[2];
  float p0 = dx * R[0] + dy * R[1] + dz * R[2];
  float p1 = dx * R[3] + dy * R[4] + dz * R[5];
  float p2 = dx * R[6] + dy * R[7] + dz * R[8];
  float pc0 = L[0] * p0 + L[1] * p1 + L[2]  * p2 + L[3];
  float pc1 = L[4] * p0 + L[5] * p1 + L[6]  * p2 + L[7];
  float pc2 = L[8] * p0 + L[9] * p1 + L[10] * p2 + L[11];
  float z  = fmaxf(pc2, 1e-5f);
  float gx = pc0 / z / WPADf * 2.f - 1.f;
  float gy = pc1 / z / HPADf * 2.f - 1.f;

  const u16* feats[3] = {f0, f1, f2};
  const int Hs[3] = {48, 24, 12}, Ws[3] = {160, 80, 40};
  u16* orow = img_pts + (size_t)pt * KIMG;
  #pragma unroll
  for (int l = 0; l < 3; ++l) {
    const int Hl = Hs[l], Wl = Ws[l];
    float ix = (gx + 1.f) * 0.5f * (float)(Wl - 1);
    float iy = (gy + 1.f) * 0.5f * (float)(Hl - 1);
    float xf0 = floorf(ix), yf0 = floorf(iy);
    float wx1 = ix - xf0, wy1 = iy - yf0;
    float wx0 = 1.f - wx1, wy0 = 1.f - wy1;
    float v = tap(feats[l], Hl, Wl, b, xf0,       yf0,       c, wx0 * wy0)
            + tap(feats[l], Hl, Wl, b, xf0 + 1.f, yf0,       c, wx1 * wy0)
            + tap(feats[l], Hl, Wl, b, xf0,       yf0 + 1.f, c, wx0 * wy1)
            + tap(feats[l], Hl, Wl, b, xf0 + 1.f, yf0 + 1.f, c, wx1 * wy1);
    orow[l * MIDC + c] = f2bf(v);
  }
}

// ============== fused GEMM (bf16 MFMA, K=448) + bias + relu ================
__global__ __launch_bounds__(256) void gemm_mfma_kernel(
    const u16*  __restrict__ Aimg,   // [100096][384] bf16 (rows>=100000 junk)
    const float* __restrict__ Apts,  // [100000][64] fp32
    const u16*  __restrict__ wg,     // frag-packed [14][128][4][8]
    const float* __restrict__ bias,
    float* __restrict__ outp)        // [100000][128]
{
  const int t = threadIdx.x, l = t & 63, wv = t >> 6;
  const int wm = wv >> 1, wn = wv & 1;
  const int lr = l & 15, lk = l >> 4;
  const int row0 = blockIdx.x * 64;

  f32x4 acc[2][4] = {};
  const u16* __restrict__ bln = wg + ((wn * 64 + lr) * 4 + lk) * 8;

  size_t ab[2];
  #pragma unroll
  for (int ag = 0; ag < 2; ++ag)
    ab[ag] = (size_t)(row0 + (wm * 2 + ag) * 16 + lr) * KIMG + lk * 8;

  #pragma unroll 4
  for (int ks = 0; ks < 12; ++ks) {
    bf16x8 A0 = *(const bf16x8*)(Aimg + ab[0] + ks * 32);
    bf16x8 A1 = *(const bf16x8*)(Aimg + ab[1] + ks * 32);
    const u16* __restrict__ bk = bln + ks * 4096;
    bf16x8 B0 = *(const bf16x8*)(bk);
    bf16x8 B1 = *(const bf16x8*)(bk + 512);
    bf16x8 B2 = *(const bf16x8*)(bk + 1024);
    bf16x8 B3 = *(const bf16x8*)(bk + 1536);
    acc[0][0] = __builtin_amdgcn_mfma_f32_16x16x32_bf16(A0, B0, acc[0][0], 0, 0, 0);
    acc[0][1] = __builtin_amdgcn_mfma_f32_16x16x32_bf16(A0, B1, acc[0][1], 0, 0, 0);
    acc[0][2] = __builtin_amdgcn_mfma_f32_16x16x32_bf16(A0, B2, acc[0][2], 0, 0, 0);
    acc[0][3] = __builtin_amdgcn_mfma_f32_16x16x32_bf16(A0, B3, acc[0][3], 0, 0, 0);
    acc[1][0] = __builtin_amdgcn_mfma_f32_16x16x32_bf16(A1, B0, acc[1][0], 0, 0, 0);
    acc[1][1] = __builtin_amdgcn_mfma_f32_16x16x32_bf16(A1, B1, acc[1][1], 0, 0, 0);
    acc[1][2] = __builtin_amdgcn_mfma_f32_16x16x32_bf16(A1, B2, acc[1][2], 0, 0, 0);
    acc[1][3] = __builtin_amdgcn_mfma_f32_16x16x32_bf16(A1, B3, acc[1][3], 0, 0, 0);
  }

  // pts tail (k 384..447): fp32 -> bf16 in-register
  int prow[2];
  #pragma unroll
  for (int ag = 0; ag < 2; ++ag)
    prow[ag] = min(row0 + (wm * 2 + ag) * 16 + lr, TOTPTS - 1);
  #pragma unroll
  for (int ks = 12; ks < 14; ++ks) {
    const int k0 = (ks - 12) * 32 + lk * 8;
    const float* __restrict__ p0 = Apts + (size_t)prow[0] * PTSC + k0;
    const float* __restrict__ p1 = Apts + (size_t)prow[1] * PTSC + k0;
    bf16x8 A0, A1;
    #pragma unroll
    for (int j = 0; j < 8; ++j) {
      A0[j] = (short)f2bf(p0[j]);
      A1[j] = (short)f2bf(p1[j]);
    }
    const u16* __restrict__ bk = bln + ks * 4096;
    bf16x8 B0 = *(const bf16x8*)(bk);
    bf16x8 B1 = *(const bf16x8*)(bk + 512);
    bf16x8 B2 = *(const bf16x8*)(bk + 1024);
    bf16x8 B3 = *(const bf16x8*)(bk + 1536);
    acc[0][0] = __builtin_amdgcn_mfma_f32_16x16x32_bf16(A0, B0, acc[0][0], 0, 0, 0);
    acc[0][1] = __builtin_amdgcn_mfma_f32_16x16x32_bf16(A0, B1, acc[0][1], 0, 0, 0);
    acc[0][2] = __builtin_amdgcn_mfma_f32_16x16x32_bf16(A0, B2, acc[0][2], 0, 0, 0);
    acc[0][3] = __builtin_amdgcn_mfma_f32_16x16x32_bf16(A0, B3, acc[0][3], 0, 0, 0);
    acc[1][0] = __builtin_amdgcn_mfma_f32_16x16x32_bf16(A1, B0, acc[1][0], 0, 0, 0);
    acc[1][1] = __builtin_amdgcn_mfma_f32_16x16x32_bf16(A1, B1, acc[1][1], 0, 0, 0);
    acc[1][2] = __builtin_amdgcn_mfma_f32_16x16x32_bf16(A1, B2, acc[1][2], 0, 0, 0);
    acc[1][3] = __builtin_amdgcn_mfma_f32_16x16x32_bf16(A1, B3, acc[1][3], 0, 0, 0);
  }

  #pragma unroll
  for (int ag = 0; ag < 2; ++ag) {
    #pragma unroll
    for (int rr = 0; rr < 4; ++rr) {
      const int row = row0 + (wm * 2 + ag) * 16 + lk * 4 + rr;
      if (row < TOTPTS) {
        float* __restrict__ po = outp + (size_t)row * OUTC;
        #pragma unroll
        for (int nf = 0; nf < 4; ++nf) {
          const int col = wn * 64 + nf * 16 + lr;
          po[col] = fmaxf(acc[ag][nf][rr] + bias[col], 0.f);
        }
      }
    }
  }
}

// ================================= host ====================================
extern "C" void kernel_launch(void* const* d_in, const int* in_sizes, int n_in,
                              void* d_out, int out_size, void* d_ws, size_t ws_size,
                              hipStream_t stream) {
  const float* f0_in  = (const float*)d_in[0];
  const float* f1_in  = (const float*)d_in[1];
  const float* f2_in  = (const float*)d_in[2];
  const float* pts    = (const float*)d_in[3];
  const float* ptsf   = (const float*)d_in[4];
  const float* l2i    = (const float*)d_in[5];
  const float* rot    = (const float*)d_in[6];
  const float* trans  = (const float*)d_in[7];
  const float* lat_w  = (const float*)d_in[8];
  const float* lat_b  = (const float*)d_in[9];
  const float* img_w  = (const float*)d_in[10];
  const float* img_b  = (const float*)d_in[11];
  const float* pts_w  = (const float*)d_in[12];
  const float* pts_b  = (const float*)d_in[13];
  const float* ibg    = (const float*)d_in[14];
  const float* ibbv   = (const float*)d_in[15];
  const float* ibm    = (const float*)d_in[16];
  const float* ibv    = (const float*)d_in[17];
  const float* pbg    = (const float*)d_in[18];
  const float* pbbv   = (const float*)d_in[19];
  const float* pbm    = (const float*)d_in[20];
  const float* pbv    = (const float*)d_in[21];
  float* outp = (float*)d_out;

  uint8_t* ws = (uint8_t*)d_ws;
  // persistent region
  const size_t off_wc   = 0;                        // 3*294912 bf16 = 1,769,472 B
  const size_t off_wg   = 1769472;                  // 57344 bf16    = 114,688 B
  const size_t off_bias = 1884160;                  // 128 f32
  const size_t off_c0   = 1884672;                  // 3,932,160 B
  const size_t off_c1   = off_c0 + 3932160;
  const size_t off_c2   = off_c1 + 983040;
  const size_t off_big  = off_c2 + 245760;          // = 7,045,632
  // transient: padded inputs live at off_big, overwritten later by img_pts
  const size_t p0_off = 0;                          // elems within big
  const size_t p1_off = 4147200;
  const size_t p2_off = 5238784;                    // end 5,539,840 elems
  // img_pts also at off_big (100096 rows * 384 bf16 = 76,873,728 B)

  u16*   wc   = (u16*)(ws + off_wc);
  u16*   wg   = (u16*)(ws + off_wg);
  float* bias = (float*)(ws + off_bias);
  u16*   c0   = (u16*)(ws + off_c0);
  u16*   cbuf = c0;
  u16*   c1   = (u16*)(ws + off_c1);
  u16*   c2   = (u16*)(ws + off_c2);
  u16*   big  = (u16*)(ws + off_big);
  u16*   imgp = big;

  // 1) zero padded region (+1 KB slack for edge-tile overreads)
  zero_kernel<<<1024, 256, 0, stream>>>((uint4*)big, (5539840 * 2 + 16384) / 16);

  // 2) NCHW f32 -> padded NHWC bf16
  nchw2nhwc_kernel<<<dim3(5, 48, 8), 256, 0, stream>>>(f0_in, big + p0_off, 48, 160);
  nchw2nhwc_kernel<<<dim3(3, 24, 8), 256, 0, stream>>>(f1_in, big + p1_off, 24, 80);
  nchw2nhwc_kernel<<<dim3(2, 12, 8), 256, 0, stream>>>(f2_in, big + p2_off, 12, 40);

  // 3) weight prep
  prep_kernel<<<3680, 256, 0, stream>>>(
      img_w, img_b, pts_w, pts_b, ibg, ibbv, ibm, ibv,
      pbg, pbbv, pbm, pbv, lat_w, wg, wc, bias);

  // 4) conv, all levels in one dispatch
  ConvParams P;
  P.base[0] = 0; P.base[1] = 240; P.base[2] = 300; P.base[3] = 318;
  P.H[0] = 48;  P.H[1] = 24; P.H[2] = 12;
  P.W[0] = 160; P.W[1] = 80; P.W[2] = 40;
  P.tx[0] = 10; P.tx[1] = 5;  P.tx[2] = 3;
  P.poff[0] = (int)p0_off; P.poff[1] = (int)p1_off; P.poff[2] = (int)p2_off;
  P.coff[0] = 0; P.coff[1] = 1966080; P.coff[2] = 2457600;
  P.woff[0] = 0; P.woff[1] = 294912;  P.woff[2] = 589824;
  conv_mfma_kernel<<<318, 256, 0, stream>>>(big, wc, lat_b, cbuf, P);

  // 5) sampling (reads conv outs, writes img_pts over the dead padded region)
  sample_kernel<<<TOTPTS / 2, 256, 0, stream>>>(
      pts, l2i, rot, trans, c0, c1, c2, imgp);

  // 6) fused GEMM + bias + BN + relu
  gemm_mfma_kernel<<<(TOTPTS + 63) / 64, 256, 0, stream>>>(
      imgp, ptsf, wg, bias, outp);

  (void)in_sizes; (void)n_in; (void)out_size; (void)ws_size;
}

// Round 4
// 184.008 us; speedup vs baseline: 6.3137x; 1.4208x over previous
//
#include <hip/hip_runtime.h>
#include <stdint.h>

using u16 = unsigned short;
typedef __attribute__((ext_vector_type(8))) short bf16x8;
typedef __attribute__((ext_vector_type(4))) float f32x4;

#define DEVI static __device__ __forceinline__

constexpr int BATCH  = 2;
constexpr int NPTS   = 50000;
constexpr int TOTPTS = BATCH * NPTS;      // 100000
constexpr int CIMG   = 256;
constexpr int MIDC   = 128;
constexpr int OUTC   = 128;
constexpr int PTSC   = 64;
constexpr int KIMG   = 384;               // 3 * 128
constexpr int KTOT   = 448;
constexpr float WPADf = 1280.f, HPADf = 384.f;
constexpr float BNEPS = 1e-3f;

DEVI u16 f2bf(float f) {                  // RNE float -> bf16 bits
  unsigned x = __float_as_uint(f);
  return (u16)((x + 0x7fffu + ((x >> 16) & 1u)) >> 16);
}
DEVI float bf2f(u16 u) { return __uint_as_float(((unsigned)u) << 16); }

// ============================ zero padded bufs =============================
__global__ __launch_bounds__(256) void zero_kernel(uint4* __restrict__ p, int n16) {
  int i = blockIdx.x * 256 + threadIdx.x;
  int stride = gridDim.x * 256;
  for (; i < n16; i += stride) p[i] = uint4{0u, 0u, 0u, 0u};
}

// ================= NCHW fp32 -> padded NHWC bf16 (per level) ===============
__global__ __launch_bounds__(256) void nchw2nhwc_kernel(
    const float* __restrict__ in, u16* __restrict__ outp, int H, int W) {
  __shared__ float s[64][33];
  const int t  = threadIdx.x;
  const int x0 = blockIdx.x * 32;
  const int y  = blockIdx.y;
  const int b  = blockIdx.z >> 2;
  const int c0 = (blockIdx.z & 3) * 64;
  #pragma unroll
  for (int i = 0; i < 8; ++i) {
    int e = t + i * 256, ci = e >> 5, xi = e & 31;
    float v = 0.f;
    if (x0 + xi < W) v = in[((size_t)(b * CIMG + c0 + ci) * H + y) * W + x0 + xi];
    s[ci][xi] = v;
  }
  __syncthreads();
  const int Wp = W + 2;
  #pragma unroll
  for (int i = 0; i < 8; ++i) {
    int e = t + i * 256, xi = e >> 6, ci = e & 63;
    if (x0 + xi < W)
      outp[((size_t)(b * (H + 2) + y + 1) * Wp + x0 + xi + 1) * CIMG + c0 + ci] =
          f2bf(s[ci][xi]);
  }
}

// ====== prep: BN-fold + bf16 frag-pack of GEMM & conv weights + bias =======
// pack layout: [ks][col(128)][s(4)][j(8)]  (k = ks*32 + s*8 + j)
__global__ __launch_bounds__(256) void prep_kernel(
    const float* __restrict__ img_w, const float* __restrict__ img_b,
    const float* __restrict__ pts_w, const float* __restrict__ pts_b,
    const float* __restrict__ ibg, const float* __restrict__ ibb,
    const float* __restrict__ ibm, const float* __restrict__ ibv,
    const float* __restrict__ pbg, const float* __restrict__ pbb,
    const float* __restrict__ pbm, const float* __restrict__ pbv,
    const float* __restrict__ lat_w,
    u16* __restrict__ wg, u16* __restrict__ wc, float* __restrict__ bias)
{
  int e = blockIdx.x * 256 + threadIdx.x;
  if (e < 57344) {                                   // GEMM pack 14*128*32
    int j = e & 7, s = (e >> 3) & 3, c = (e >> 5) & 127, ks = e >> 12;
    int k = ks * 32 + s * 8 + j;
    float s1 = ibg[c] * rsqrtf(ibv[c] + BNEPS);
    float s2 = pbg[c] * rsqrtf(pbv[c] + BNEPS);
    float w = (k < KIMG) ? img_w[c * KIMG + k] * s1
                         : pts_w[c * PTSC + (k - KIMG)] * s2;
    wg[e] = f2bf(w);
    if (e < OUTC) {
      float t1 = ibg[e] * rsqrtf(ibv[e] + BNEPS);
      float t2 = pbg[e] * rsqrtf(pbv[e] + BNEPS);
      bias[e] = (img_b[e] - ibm[e]) * t1 + ibb[e] +
                (pts_b[e] - pbm[e]) * t2 + pbb[e];
    }
  } else if (e < 57344 + 3 * 294912) {               // conv pack 3*72*128*32
    int q = e - 57344;
    int l = q / 294912, r = q % 294912;
    int j = r & 7, s = (r >> 3) & 3, c = (r >> 5) & 127, ks = r >> 12;
    int k = ks * 32 + s * 8 + j;                     // 0..2303
    int tap = k >> 8, ic = k & 255;
    float w = lat_w[(((size_t)l * 128 + c) * 256 + ic) * 9 + tap];
    wc[(size_t)l * 294912 + r] = f2bf(w);
  }
}

// =================== conv as implicit-GEMM MFMA (all levels) ===============
struct ConvParams {
  int base[4];          // block-id level boundaries
  int H[3], W[3], tx[3];
  int poff[3];          // padded-input offsets (elements)
  int coff[3];          // conv-out offsets (elements)
  int woff[3];          // weight-pack offsets (elements)
};

__global__ __launch_bounds__(256) void conv_mfma_kernel(
    const u16* __restrict__ pad, const u16* __restrict__ wc,
    const float* __restrict__ lat_b, u16* __restrict__ outbuf, ConvParams P)
{
  const int bid = blockIdx.x;
  const int lvl = (bid >= P.base[1]) + (bid >= P.base[2]);
  const int local = bid - P.base[lvl];
  const int H = P.H[lvl], W = P.W[lvl], tilesx = P.tx[lvl];
  const int nxy = tilesx * (H >> 2);
  const int b = local / nxy;
  const int r = local % nxy;
  const int ty = r / tilesx, tx = r % tilesx;
  const int y0 = ty * 4, x0 = tx * 16;
  const u16* __restrict__ pin = pad + P.poff[lvl];
  const u16* __restrict__ wl  = wc + P.woff[lvl];
  u16* __restrict__ outp = outbuf + P.coff[lvl];

  const int t = threadIdx.x, l = t & 63, wv = t >> 6;
  const int wm = wv >> 1, wn = wv & 1;
  const int lr = l & 15, lk = l >> 4;
  const int Wp = W + 2;

  f32x4 acc[2][4] = {};

  size_t abase[2];
  #pragma unroll
  for (int ag = 0; ag < 2; ++ag)
    abase[ag] = (((size_t)(b * (H + 2) + y0 + wm * 2 + ag) * Wp) + x0 + lr) * CIMG + lk * 8;
  const u16* __restrict__ bln = wl + ((wn * 64 + lr) * 4 + lk) * 8;  // lane base

  for (int tap = 0; tap < 9; ++tap) {
    const int ky = tap / 3, kx = tap - ky * 3;
    const size_t toff = ((size_t)ky * Wp + kx) * CIMG;
    const u16* __restrict__ a0 = pin + abase[0] + toff;
    const u16* __restrict__ a1 = pin + abase[1] + toff;
    const u16* __restrict__ bt = bln + (size_t)tap * 8 * 4096;  // ks stride 4096 elems
    #pragma unroll
    for (int icc = 0; icc < 8; ++icc) {
      bf16x8 A0 = *(const bf16x8*)(a0 + icc * 32);
      bf16x8 A1 = *(const bf16x8*)(a1 + icc * 32);
      bf16x8 B0 = *(const bf16x8*)(bt + icc * 4096);
      bf16x8 B1 = *(const bf16x8*)(bt + icc * 4096 + 512);
      bf16x8 B2 = *(const bf16x8*)(bt + icc * 4096 + 1024);
      bf16x8 B3 = *(const bf16x8*)(bt + icc * 4096 + 1536);
      acc[0][0] = __builtin_amdgcn_mfma_f32_16x16x32_bf16(A0, B0, acc[0][0], 0, 0, 0);
      acc[0][1] = __builtin_amdgcn_mfma_f32_16x16x32_bf16(A0, B1, acc[0][1], 0, 0, 0);
      acc[0][2] = __builtin_amdgcn_mfma_f32_16x16x32_bf16(A0, B2, acc[0][2], 0, 0, 0);
      acc[0][3] = __builtin_amdgcn_mfma_f32_16x16x32_bf16(A0, B3, acc[0][3], 0, 0, 0);
      acc[1][0] = __builtin_amdgcn_mfma_f32_16x16x32_bf16(A1, B0, acc[1][0], 0, 0, 0);
      acc[1][1] = __builtin_amdgcn_mfma_f32_16x16x32_bf16(A1, B1, acc[1][1], 0, 0, 0);
      acc[1][2] = __builtin_amdgcn_mfma_f32_16x16x32_bf16(A1, B2, acc[1][2], 0, 0, 0);
      acc[1][3] = __builtin_amdgcn_mfma_f32_16x16x32_bf16(A1, B3, acc[1][3], 0, 0, 0);
    }
  }

  const int ocb = wn * 64;
  #pragma unroll
  for (int ag = 0; ag < 2; ++ag) {
    const int y = y0 + wm * 2 + ag;
    #pragma unroll
    for (int rr = 0; rr < 4; ++rr) {
      const int x = x0 + lk * 4 + rr;
      if (x < W) {
        const size_t o = ((size_t)(b * H + y) * W + x) * MIDC;
        #pragma unroll
        for (int nf = 0; nf < 4; ++nf) {
          const int oc = ocb + nf * 16 + lr;
          outp[o + oc] = f2bf(acc[ag][nf][rr] + lat_b[lvl * 128 + oc]);
        }
      }
    }
  }
}

// ===== projection + bilinear sampling -> img_pts (4 ch/lane, branchless) ===
__global__ __launch_bounds__(256) void sample_kernel(
    const float* __restrict__ pts, const float* __restrict__ l2i,
    const float* __restrict__ rot, const float* __restrict__ trans,
    const u16* __restrict__ f0, const u16* __restrict__ f1,
    const u16* __restrict__ f2, u16* __restrict__ img_pts)
{
  const int t  = threadIdx.x;
  const int lq = t & 31;                   // channel quad 0..31 (ch = lq*4..lq*4+3)
  const int pt = blockIdx.x * 8 + (t >> 5);
  const int b  = pt / NPTS;

  const float* P = pts + (size_t)pt * 3;
  const float* T = trans + b * 3;
  const float* R = rot + b * 9;
  const float* L = l2i + b * 16;
  float dx = P[0] - T[0], dy = P[1] - T[1], dz = P[2] - T[2];
  float p0 = dx * R[0] + dy * R[1] + dz * R[2];
  float p1 = dx * R[3] + dy * R[4] + dz * R[5];
  float p2 = dx * R[6] + dy * R[7] + dz * R[8];
  float pc0 = L[0] * p0 + L[1] * p1 + L[2]  * p2 + L[3];
  float pc1 = L[4] * p0 + L[5] * p1 + L[6]  * p2 + L[7];
  float pc2 = L[8] * p0 + L[9] * p1 + L[10] * p2 + L[11];
  float z  = fmaxf(pc2, 1e-5f);
  float gx = pc0 / z / WPADf * 2.f - 1.f;
  float gy = pc1 / z / HPADf * 2.f - 1.f;

  const u16* __restrict__ feats[3] = {f0, f1, f2};
  const int Hs[3] = {48, 24, 12}, Ws[3] = {160, 80, 40};
  u16* __restrict__ orow = img_pts + (size_t)pt * KIMG + lq * 4;

  #pragma unroll
  for (int l = 0; l < 3; ++l) {
    const int Hl = Hs[l], Wl = Ws[l];
    const float Wm1 = (float)(Wl - 1), Hm1 = (float)(Hl - 1);
    float ix = (gx + 1.f) * 0.5f * Wm1;
    float iy = (gy + 1.f) * 0.5f * Hm1;
    float xf = floorf(ix), yf = floorf(iy);
    float wx1 = ix - xf, wy1 = iy - yf;
    float wx0 = 1.f - wx1, wy0 = 1.f - wy1;
    // validity folded into weights (reference: clip index, zero invalid taps)
    float ax0 = (xf >= 0.f        && xf <= Wm1)        ? wx0 : 0.f;
    float ax1 = (xf + 1.f >= 0.f  && xf + 1.f <= Wm1)  ? wx1 : 0.f;
    float ay0 = (yf >= 0.f        && yf <= Hm1)        ? wy0 : 0.f;
    float ay1 = (yf + 1.f >= 0.f  && yf + 1.f <= Hm1)  ? wy1 : 0.f;
    float w00 = ax0 * ay0, w10 = ax1 * ay0, w01 = ax0 * ay1, w11 = ax1 * ay1;
    // clamped integer indices (always-in-bounds addresses)
    int xi0 = (int)fminf(fmaxf(xf,       0.f), Wm1);
    int xi1 = (int)fminf(fmaxf(xf + 1.f, 0.f), Wm1);
    int yi0 = (int)fminf(fmaxf(yf,       0.f), Hm1);
    int yi1 = (int)fminf(fmaxf(yf + 1.f, 0.f), Hm1);

    const u16* __restrict__ fb = feats[l] + ((size_t)b * Hl * Wl) * MIDC + lq * 4;
    uint2 q00 = *(const uint2*)(fb + (size_t)(yi0 * Wl + xi0) * MIDC);
    uint2 q10 = *(const uint2*)(fb + (size_t)(yi0 * Wl + xi1) * MIDC);
    uint2 q01 = *(const uint2*)(fb + (size_t)(yi1 * Wl + xi0) * MIDC);
    uint2 q11 = *(const uint2*)(fb + (size_t)(yi1 * Wl + xi1) * MIDC);

    float r0, r1, r2, r3;
    r0  = __uint_as_float(q00.x << 16)         * w00;
    r1  = __uint_as_float(q00.x & 0xffff0000u) * w00;
    r2  = __uint_as_float(q00.y << 16)         * w00;
    r3  = __uint_as_float(q00.y & 0xffff0000u) * w00;
    r0 += __uint_as_float(q10.x << 16)         * w10;
    r1 += __uint_as_float(q10.x & 0xffff0000u) * w10;
    r2 += __uint_as_float(q10.y << 16)         * w10;
    r3 += __uint_as_float(q10.y & 0xffff0000u) * w10;
    r0 += __uint_as_float(q01.x << 16)         * w01;
    r1 += __uint_as_float(q01.x & 0xffff0000u) * w01;
    r2 += __uint_as_float(q01.y << 16)         * w01;
    r3 += __uint_as_float(q01.y & 0xffff0000u) * w01;
    r0 += __uint_as_float(q11.x << 16)         * w11;
    r1 += __uint_as_float(q11.x & 0xffff0000u) * w11;
    r2 += __uint_as_float(q11.y << 16)         * w11;
    r3 += __uint_as_float(q11.y & 0xffff0000u) * w11;

    uint2 o;
    o.x = (unsigned)f2bf(r0) | ((unsigned)f2bf(r1) << 16);
    o.y = (unsigned)f2bf(r2) | ((unsigned)f2bf(r3) << 16);
    *(uint2*)(orow + l * MIDC) = o;
  }
}

// ============== fused GEMM (bf16 MFMA, K=448) + bias + relu ================
__global__ __launch_bounds__(256) void gemm_mfma_kernel(
    const u16*  __restrict__ Aimg,   // [100096][384] bf16 (rows>=100000 junk)
    const float* __restrict__ Apts,  // [100000][64] fp32
    const u16*  __restrict__ wg,     // frag-packed [14][128][4][8]
    const float* __restrict__ bias,
    float* __restrict__ outp)        // [100000][128]
{
  const int t = threadIdx.x, l = t & 63, wv = t >> 6;
  const int wm = wv >> 1, wn = wv & 1;
  const int lr = l & 15, lk = l >> 4;
  const int row0 = blockIdx.x * 64;

  f32x4 acc[2][4] = {};
  const u16* __restrict__ bln = wg + ((wn * 64 + lr) * 4 + lk) * 8;

  size_t ab[2];
  #pragma unroll
  for (int ag = 0; ag < 2; ++ag)
    ab[ag] = (size_t)(row0 + (wm * 2 + ag) * 16 + lr) * KIMG + lk * 8;

  #pragma unroll 4
  for (int ks = 0; ks < 12; ++ks) {
    bf16x8 A0 = *(const bf16x8*)(Aimg + ab[0] + ks * 32);
    bf16x8 A1 = *(const bf16x8*)(Aimg + ab[1] + ks * 32);
    const u16* __restrict__ bk = bln + ks * 4096;
    bf16x8 B0 = *(const bf16x8*)(bk);
    bf16x8 B1 = *(const bf16x8*)(bk + 512);
    bf16x8 B2 = *(const bf16x8*)(bk + 1024);
    bf16x8 B3 = *(const bf16x8*)(bk + 1536);
    acc[0][0] = __builtin_amdgcn_mfma_f32_16x16x32_bf16(A0, B0, acc[0][0], 0, 0, 0);
    acc[0][1] = __builtin_amdgcn_mfma_f32_16x16x32_bf16(A0, B1, acc[0][1], 0, 0, 0);
    acc[0][2] = __builtin_amdgcn_mfma_f32_16x16x32_bf16(A0, B2, acc[0][2], 0, 0, 0);
    acc[0][3] = __builtin_amdgcn_mfma_f32_16x16x32_bf16(A0, B3, acc[0][3], 0, 0, 0);
    acc[1][0] = __builtin_amdgcn_mfma_f32_16x16x32_bf16(A1, B0, acc[1][0], 0, 0, 0);
    acc[1][1] = __builtin_amdgcn_mfma_f32_16x16x32_bf16(A1, B1, acc[1][1], 0, 0, 0);
    acc[1][2] = __builtin_amdgcn_mfma_f32_16x16x32_bf16(A1, B2, acc[1][2], 0, 0, 0);
    acc[1][3] = __builtin_amdgcn_mfma_f32_16x16x32_bf16(A1, B3, acc[1][3], 0, 0, 0);
  }

  // pts tail (k 384..447): fp32 -> bf16 in-register
  int prow[2];
  #pragma unroll
  for (int ag = 0; ag < 2; ++ag)
    prow[ag] = min(row0 + (wm * 2 + ag) * 16 + lr, TOTPTS - 1);
  #pragma unroll
  for (int ks = 12; ks < 14; ++ks) {
    const int k0 = (ks - 12) * 32 + lk * 8;
    const float* __restrict__ p0 = Apts + (size_t)prow[0] * PTSC + k0;
    const float* __restrict__ p1 = Apts + (size_t)prow[1] * PTSC + k0;
    bf16x8 A0, A1;
    #pragma unroll
    for (int j = 0; j < 8; ++j) {
      A0[j] = (short)f2bf(p0[j]);
      A1[j] = (short)f2bf(p1[j]);
    }
    const u16* __restrict__ bk = bln + ks * 4096;
    bf16x8 B0 = *(const bf16x8*)(bk);
    bf16x8 B1 = *(const bf16x8*)(bk + 512);
    bf16x8 B2 = *(const bf16x8*)(bk + 1024);
    bf16x8 B3 = *(const bf16x8*)(bk + 1536);
    acc[0][0] = __builtin_amdgcn_mfma_f32_16x16x32_bf16(A0, B0, acc[0][0], 0, 0, 0);
    acc[0][1] = __builtin_amdgcn_mfma_f32_16x16x32_bf16(A0, B1, acc[0][1], 0, 0, 0);
    acc[0][2] = __builtin_amdgcn_mfma_f32_16x16x32_bf16(A0, B2, acc[0][2], 0, 0, 0);
    acc[0][3] = __builtin_amdgcn_mfma_f32_16x16x32_bf16(A0, B3, acc[0][3], 0, 0, 0);
    acc[1][0] = __builtin_amdgcn_mfma_f32_16x16x32_bf16(A1, B0, acc[1][0], 0, 0, 0);
    acc[1][1] = __builtin_amdgcn_mfma_f32_16x16x32_bf16(A1, B1, acc[1][1], 0, 0, 0);
    acc[1][2] = __builtin_amdgcn_mfma_f32_16x16x32_bf16(A1, B2, acc[1][2], 0, 0, 0);
    acc[1][3] = __builtin_amdgcn_mfma_f32_16x16x32_bf16(A1, B3, acc[1][3], 0, 0, 0);
  }

  #pragma unroll
  for (int ag = 0; ag < 2; ++ag) {
    #pragma unroll
    for (int rr = 0; rr < 4; ++rr) {
      const int row = row0 + (wm * 2 + ag) * 16 + lk * 4 + rr;
      if (row < TOTPTS) {
        float* __restrict__ po = outp + (size_t)row * OUTC;
        #pragma unroll
        for (int nf = 0; nf < 4; ++nf) {
          const int col = wn * 64 + nf * 16 + lr;
          po[col] = fmaxf(acc[ag][nf][rr] + bias[col], 0.f);
        }
      }
    }
  }
}

// ================================= host ====================================
extern "C" void kernel_launch(void* const* d_in, const int* in_sizes, int n_in,
                              void* d_out, int out_size, void* d_ws, size_t ws_size,
                              hipStream_t stream) {
  const float* f0_in  = (const float*)d_in[0];
  const float* f1_in  = (const float*)d_in[1];
  const float* f2_in  = (const float*)d_in[2];
  const float* pts    = (const float*)d_in[3];
  const float* ptsf   = (const float*)d_in[4];
  const float* l2i    = (const float*)d_in[5];
  const float* rot    = (const float*)d_in[6];
  const float* trans  = (const float*)d_in[7];
  const float* lat_w  = (const float*)d_in[8];
  const float* lat_b  = (const float*)d_in[9];
  const float* img_w  = (const float*)d_in[10];
  const float* img_b  = (const float*)d_in[11];
  const float* pts_w  = (const float*)d_in[12];
  const float* pts_b  = (const float*)d_in[13];
  const float* ibg    = (const float*)d_in[14];
  const float* ibbv   = (const float*)d_in[15];
  const float* ibm    = (const float*)d_in[16];
  const float* ibv    = (const float*)d_in[17];
  const float* pbg    = (const float*)d_in[18];
  const float* pbbv   = (const float*)d_in[19];
  const float* pbm    = (const float*)d_in[20];
  const float* pbv    = (const float*)d_in[21];
  float* outp = (float*)d_out;

  uint8_t* ws = (uint8_t*)d_ws;
  // persistent region
  const size_t off_wc   = 0;                        // 3*294912 bf16 = 1,769,472 B
  const size_t off_wg   = 1769472;                  // 57344 bf16    = 114,688 B
  const size_t off_bias = 1884160;                  // 128 f32
  const size_t off_c0   = 1884672;                  // 3,932,160 B
  const size_t off_c1   = off_c0 + 3932160;
  const size_t off_c2   = off_c1 + 983040;
  const size_t off_big  = off_c2 + 245760;          // = 7,045,632
  // transient: padded inputs live at off_big, overwritten later by img_pts
  const size_t p0_off = 0;                          // elems within big
  const size_t p1_off = 4147200;
  const size_t p2_off = 5238784;                    // end 5,539,840 elems
  // img_pts also at off_big (100096 rows * 384 bf16 = 76,873,728 B)

  u16*   wc   = (u16*)(ws + off_wc);
  u16*   wg   = (u16*)(ws + off_wg);
  float* bias = (float*)(ws + off_bias);
  u16*   c0   = (u16*)(ws + off_c0);
  u16*   cbuf = c0;
  u16*   c1   = (u16*)(ws + off_c1);
  u16*   c2   = (u16*)(ws + off_c2);
  u16*   big  = (u16*)(ws + off_big);
  u16*   imgp = big;

  // 1) zero padded region (+1 KB slack for edge-tile overreads)
  zero_kernel<<<1024, 256, 0, stream>>>((uint4*)big, (5539840 * 2 + 16384) / 16);

  // 2) NCHW f32 -> padded NHWC bf16
  nchw2nhwc_kernel<<<dim3(5, 48, 8), 256, 0, stream>>>(f0_in, big + p0_off, 48, 160);
  nchw2nhwc_kernel<<<dim3(3, 24, 8), 256, 0, stream>>>(f1_in, big + p1_off, 24, 80);
  nchw2nhwc_kernel<<<dim3(2, 12, 8), 256, 0, stream>>>(f2_in, big + p2_off, 12, 40);

  // 3) weight prep
  prep_kernel<<<3680, 256, 0, stream>>>(
      img_w, img_b, pts_w, pts_b, ibg, ibbv, ibm, ibv,
      pbg, pbbv, pbm, pbv, lat_w, wg, wc, bias);

  // 4) conv, all levels in one dispatch
  ConvParams P;
  P.base[0] = 0; P.base[1] = 240; P.base[2] = 300; P.base[3] = 318;
  P.H[0] = 48;  P.H[1] = 24; P.H[2] = 12;
  P.W[0] = 160; P.W[1] = 80; P.W[2] = 40;
  P.tx[0] = 10; P.tx[1] = 5;  P.tx[2] = 3;
  P.poff[0] = (int)p0_off; P.poff[1] = (int)p1_off; P.poff[2] = (int)p2_off;
  P.coff[0] = 0; P.coff[1] = 1966080; P.coff[2] = 2457600;
  P.woff[0] = 0; P.woff[1] = 294912;  P.woff[2] = 589824;
  conv_mfma_kernel<<<318, 256, 0, stream>>>(big, wc, lat_b, cbuf, P);

  // 5) sampling (reads conv outs, writes img_pts over the dead padded region)
  sample_kernel<<<TOTPTS / 8, 256, 0, stream>>>(
      pts, l2i, rot, trans, c0, c1, c2, imgp);

  // 6) fused GEMM + bias + BN + relu
  gemm_mfma_kernel<<<(TOTPTS + 63) / 64, 256, 0, stream>>>(
      imgp, ptsf, wg, bias, outp);

  (void)in_sizes; (void)n_in; (void)out_size; (void)ws_size;
}

// Round 5
// 158.287 us; speedup vs baseline: 7.3396x; 1.1625x over previous
//
#include <hip/hip_runtime.h>
#include <stdint.h>

using u16 = unsigned short;
typedef __attribute__((ext_vector_type(8))) short bf16x8;
typedef __attribute__((ext_vector_type(4))) float f32x4;

#define DEVI static __device__ __forceinline__

constexpr int BATCH  = 2;
constexpr int NPTS   = 50000;
constexpr int TOTPTS = BATCH * NPTS;      // 100000
constexpr int CIMG   = 256;
constexpr int MIDC   = 128;
constexpr int OUTC   = 128;
constexpr int PTSC   = 64;
constexpr int KIMG   = 384;               // 3 * 128
constexpr int KTOT   = 448;
constexpr float WPADf = 1280.f, HPADf = 384.f;
constexpr float BNEPS = 1e-3f;

DEVI u16 f2bf(float f) {                  // RNE float -> bf16 bits
  unsigned x = __float_as_uint(f);
  return (u16)((x + 0x7fffu + ((x >> 16) & 1u)) >> 16);
}
DEVI float bf2f(u16 u) { return __uint_as_float(((unsigned)u) << 16); }

// ============================ zero padded bufs =============================
__global__ __launch_bounds__(256) void zero_kernel(uint4* __restrict__ p, int n16) {
  int i = blockIdx.x * 256 + threadIdx.x;
  int stride = gridDim.x * 256;
  for (; i < n16; i += stride) p[i] = uint4{0u, 0u, 0u, 0u};
}

// ================= NCHW fp32 -> padded NHWC bf16 (per level) ===============
__global__ __launch_bounds__(256) void nchw2nhwc_kernel(
    const float* __restrict__ in, u16* __restrict__ outp, int H, int W) {
  __shared__ float s[64][33];
  const int t  = threadIdx.x;
  const int x0 = blockIdx.x * 32;
  const int y  = blockIdx.y;
  const int b  = blockIdx.z >> 2;
  const int c0 = (blockIdx.z & 3) * 64;
  #pragma unroll
  for (int i = 0; i < 8; ++i) {
    int e = t + i * 256, ci = e >> 5, xi = e & 31;
    float v = 0.f;
    if (x0 + xi < W) v = in[((size_t)(b * CIMG + c0 + ci) * H + y) * W + x0 + xi];
    s[ci][xi] = v;
  }
  __syncthreads();
  const int Wp = W + 2;
  #pragma unroll
  for (int i = 0; i < 8; ++i) {
    int e = t + i * 256, xi = e >> 6, ci = e & 63;
    if (x0 + xi < W)
      outp[((size_t)(b * (H + 2) + y + 1) * Wp + x0 + xi + 1) * CIMG + c0 + ci] =
          f2bf(s[ci][xi]);
  }
}

// ====== prep: BN-fold + bf16 frag-pack of GEMM & conv weights + bias =======
// pack layout: [ks][col(128)][s(4)][j(8)]  (k = ks*32 + s*8 + j)
__global__ __launch_bounds__(256) void prep_kernel(
    const float* __restrict__ img_w, const float* __restrict__ img_b,
    const float* __restrict__ pts_w, const float* __restrict__ pts_b,
    const float* __restrict__ ibg, const float* __restrict__ ibb,
    const float* __restrict__ ibm, const float* __restrict__ ibv,
    const float* __restrict__ pbg, const float* __restrict__ pbb,
    const float* __restrict__ pbm, const float* __restrict__ pbv,
    const float* __restrict__ lat_w,
    u16* __restrict__ wg, u16* __restrict__ wc, float* __restrict__ bias)
{
  int e = blockIdx.x * 256 + threadIdx.x;
  if (e < 57344) {                                   // GEMM pack 14*128*32
    int j = e & 7, s = (e >> 3) & 3, c = (e >> 5) & 127, ks = e >> 12;
    int k = ks * 32 + s * 8 + j;
    float s1 = ibg[c] * rsqrtf(ibv[c] + BNEPS);
    float s2 = pbg[c] * rsqrtf(pbv[c] + BNEPS);
    float w = (k < KIMG) ? img_w[c * KIMG + k] * s1
                         : pts_w[c * PTSC + (k - KIMG)] * s2;
    wg[e] = f2bf(w);
    if (e < OUTC) {
      float t1 = ibg[e] * rsqrtf(ibv[e] + BNEPS);
      float t2 = pbg[e] * rsqrtf(pbv[e] + BNEPS);
      bias[e] = (img_b[e] - ibm[e]) * t1 + ibb[e] +
                (pts_b[e] - pbm[e]) * t2 + pbb[e];
    }
  } else if (e < 57344 + 3 * 294912) {               // conv pack 3*72*128*32
    int q = e - 57344;
    int l = q / 294912, r = q % 294912;
    int j = r & 7, s = (r >> 3) & 3, c = (r >> 5) & 127, ks = r >> 12;
    int k = ks * 32 + s * 8 + j;                     // 0..2303
    int tap = k >> 8, ic = k & 255;
    float w = lat_w[(((size_t)l * 128 + c) * 256 + ic) * 9 + tap];
    wc[(size_t)l * 294912 + r] = f2bf(w);
  }
}

// =================== conv as implicit-GEMM MFMA (all levels) ===============
// LDS-staged A (6x18x256 bf16, swizzled), register-ring prefetched B.
struct ConvParams {
  int base[4];          // block-id level boundaries
  int H[3], W[3], tx[3];
  int poff[3];          // padded-input offsets (elements)
  int coff[3];          // conv-out offsets (elements)
  int woff[3];          // weight-pack offsets (elements)
};

__global__ __launch_bounds__(256, 2) void conv_mfma_kernel(
    const u16* __restrict__ pad, const u16* __restrict__ wc,
    const float* __restrict__ lat_b, u16* __restrict__ outbuf, ConvParams P)
{
  __shared__ u16 sA[6 * 18 * 256];                  // 55,296 B
  const int bid = blockIdx.x;
  const int lvl = (bid >= P.base[1]) + (bid >= P.base[2]);
  const int local = bid - P.base[lvl];
  const int H = P.H[lvl], W = P.W[lvl], tilesx = P.tx[lvl];
  const int nxy = tilesx * (H >> 2);
  const int b = local / nxy;
  const int r = local % nxy;
  const int ty = r / tilesx, tx = r - ty * tilesx;
  const int y0 = ty * 4, x0 = tx * 16;
  const int Wp = W + 2;
  const u16* __restrict__ pin = pad + P.poff[lvl];
  const u16* __restrict__ wl  = wc + P.woff[lvl];
  u16* __restrict__ outp = outbuf + P.coff[lvl];

  const int t = threadIdx.x, l = t & 63, wv = t >> 6;
  const int wm = wv >> 1, wn = wv & 1;
  const int lr = l & 15, lk = l >> 4;

  // ---- stage A tile: rows y0..y0+5 (padded idx), px x0..x0+17, 256 ch ----
  // LDS[(row*18+px)*512 + (bo ^ ((px&7)<<4))] = global[row][x0+px][bo]
  {
    const int pxi = l >> 5;                  // 0/1: px within 1KB chunk
    const int bo  = (l & 31) * 16;           // byte within 512B px block
    #pragma unroll
    for (int it = 0; it < 14; ++it) {
      const int ch = wv + it * 4;            // chunk 0..53 (1KB = 2 px)
      if (ch < 54) {
        const int rr2 = ch / 9;
        const int pp  = (ch % 9) * 2;
        const int px  = pp + pxi;
        const u16* src = pin +
            (((size_t)(b * (H + 2) + y0 + rr2) * Wp) + x0 + px) * CIMG + (bo >> 1);
        uint4 v = *(const uint4*)src;
        *(uint4*)((char*)sA + ch * 1024 + pxi * 512 + (bo ^ ((px & 7) << 4))) = v;
      }
    }
  }
  __syncthreads();

  f32x4 acc[2][4] = {};
  bf16x8 Ab[2][2], Bb[4][4];
  const u16* __restrict__ bln = wl + ((wn * 64 + lr) * 4 + lk) * 8;

  auto loadB = [&](int ks) {
    const u16* __restrict__ bk = bln + (size_t)ks * 4096;
    Bb[ks & 3][0] = *(const bf16x8*)(bk);
    Bb[ks & 3][1] = *(const bf16x8*)(bk + 512);
    Bb[ks & 3][2] = *(const bf16x8*)(bk + 1024);
    Bb[ks & 3][3] = *(const bf16x8*)(bk + 1536);
  };
  auto loadA = [&](int ks) {
    const int tap = ks >> 3, icc = ks & 7;
    const int ky = tap / 3, kx = tap - ky * 3;
    const int px = lr + kx;
    const int swz = (px & 7) << 4;
    #pragma unroll
    for (int ag = 0; ag < 2; ++ag) {
      const int row = wm * 2 + ag + ky;
      const int ba = (row * 18 + px) * 512 + ((icc * 64 + lk * 16) ^ swz);
      Ab[ks & 1][ag] = *(const bf16x8*)((const char*)sA + ba);
    }
  };

  loadB(0); loadB(1); loadB(2); loadB(3);
  loadA(0);
  #pragma unroll
  for (int ks = 0; ks < 72; ++ks) {
    if (ks < 71) loadA(ks + 1);
    const bf16x8 A0 = Ab[ks & 1][0], A1 = Ab[ks & 1][1];
    const bf16x8 B0 = Bb[ks & 3][0], B1 = Bb[ks & 3][1];
    const bf16x8 B2 = Bb[ks & 3][2], B3 = Bb[ks & 3][3];
    acc[0][0] = __builtin_amdgcn_mfma_f32_16x16x32_bf16(A0, B0, acc[0][0], 0, 0, 0);
    acc[0][1] = __builtin_amdgcn_mfma_f32_16x16x32_bf16(A0, B1, acc[0][1], 0, 0, 0);
    acc[0][2] = __builtin_amdgcn_mfma_f32_16x16x32_bf16(A0, B2, acc[0][2], 0, 0, 0);
    acc[0][3] = __builtin_amdgcn_mfma_f32_16x16x32_bf16(A0, B3, acc[0][3], 0, 0, 0);
    acc[1][0] = __builtin_amdgcn_mfma_f32_16x16x32_bf16(A1, B0, acc[1][0], 0, 0, 0);
    acc[1][1] = __builtin_amdgcn_mfma_f32_16x16x32_bf16(A1, B1, acc[1][1], 0, 0, 0);
    acc[1][2] = __builtin_amdgcn_mfma_f32_16x16x32_bf16(A1, B2, acc[1][2], 0, 0, 0);
    acc[1][3] = __builtin_amdgcn_mfma_f32_16x16x32_bf16(A1, B3, acc[1][3], 0, 0, 0);
    if (ks + 4 < 72) loadB(ks + 4);
  }

  const int ocb = wn * 64;
  #pragma unroll
  for (int ag = 0; ag < 2; ++ag) {
    const int y = y0 + wm * 2 + ag;
    #pragma unroll
    for (int rr = 0; rr < 4; ++rr) {
      const int x = x0 + lk * 4 + rr;
      if (x < W) {
        const size_t o = ((size_t)(b * H + y) * W + x) * MIDC;
        #pragma unroll
        for (int nf = 0; nf < 4; ++nf) {
          const int oc = ocb + nf * 16 + lr;
          outp[o + oc] = f2bf(acc[ag][nf][rr] + lat_b[lvl * 128 + oc]);
        }
      }
    }
  }
}

// ===== projection + bilinear sampling -> img_pts (4 ch/lane, branchless) ===
__global__ __launch_bounds__(256) void sample_kernel(
    const float* __restrict__ pts, const float* __restrict__ l2i,
    const float* __restrict__ rot, const float* __restrict__ trans,
    const u16* __restrict__ f0, const u16* __restrict__ f1,
    const u16* __restrict__ f2, u16* __restrict__ img_pts)
{
  const int t  = threadIdx.x;
  const int lq = t & 31;                   // channel quad 0..31 (ch = lq*4..lq*4+3)
  const int pt = blockIdx.x * 8 + (t >> 5);
  const int b  = pt / NPTS;

  const float* P = pts + (size_t)pt * 3;
  const float* T = trans + b * 3;
  const float* R = rot + b * 9;
  const float* L = l2i + b * 16;
  float dx = P[0] - T[0], dy = P[1] - T[1], dz = P[2] - T[2];
  float p0 = dx * R[0] + dy * R[1] + dz * R[2];
  float p1 = dx * R[3] + dy * R[4] + dz * R[5];
  float p2 = dx * R[6] + dy * R[7] + dz * R[8];
  float pc0 = L[0] * p0 + L[1] * p1 + L[2]  * p2 + L[3];
  float pc1 = L[4] * p0 + L[5] * p1 + L[6]  * p2 + L[7];
  float pc2 = L[8] * p0 + L[9] * p1 + L[10] * p2 + L[11];
  float z  = fmaxf(pc2, 1e-5f);
  float gx = pc0 / z / WPADf * 2.f - 1.f;
  float gy = pc1 / z / HPADf * 2.f - 1.f;

  const u16* __restrict__ feats[3] = {f0, f1, f2};
  const int Hs[3] = {48, 24, 12}, Ws[3] = {160, 80, 40};
  u16* __restrict__ orow = img_pts + (size_t)pt * KIMG + lq * 4;

  #pragma unroll
  for (int l = 0; l < 3; ++l) {
    const int Hl = Hs[l], Wl = Ws[l];
    const float Wm1 = (float)(Wl - 1), Hm1 = (float)(Hl - 1);
    float ix = (gx + 1.f) * 0.5f * Wm1;
    float iy = (gy + 1.f) * 0.5f * Hm1;
    float xf = floorf(ix), yf = floorf(iy);
    float wx1 = ix - xf, wy1 = iy - yf;
    float wx0 = 1.f - wx1, wy0 = 1.f - wy1;
    // validity folded into weights (reference: clip index, zero invalid taps)
    float ax0 = (xf >= 0.f        && xf <= Wm1)        ? wx0 : 0.f;
    float ax1 = (xf + 1.f >= 0.f  && xf + 1.f <= Wm1)  ? wx1 : 0.f;
    float ay0 = (yf >= 0.f        && yf <= Hm1)        ? wy0 : 0.f;
    float ay1 = (yf + 1.f >= 0.f  && yf + 1.f <= Hm1)  ? wy1 : 0.f;
    float w00 = ax0 * ay0, w10 = ax1 * ay0, w01 = ax0 * ay1, w11 = ax1 * ay1;
    // clamped integer indices (always-in-bounds addresses)
    int xi0 = (int)fminf(fmaxf(xf,       0.f), Wm1);
    int xi1 = (int)fminf(fmaxf(xf + 1.f, 0.f), Wm1);
    int yi0 = (int)fminf(fmaxf(yf,       0.f), Hm1);
    int yi1 = (int)fminf(fmaxf(yf + 1.f, 0.f), Hm1);

    const u16* __restrict__ fb = feats[l] + ((size_t)b * Hl * Wl) * MIDC + lq * 4;
    uint2 q00 = *(const uint2*)(fb + (size_t)(yi0 * Wl + xi0) * MIDC);
    uint2 q10 = *(const uint2*)(fb + (size_t)(yi0 * Wl + xi1) * MIDC);
    uint2 q01 = *(const uint2*)(fb + (size_t)(yi1 * Wl + xi0) * MIDC);
    uint2 q11 = *(const uint2*)(fb + (size_t)(yi1 * Wl + xi1) * MIDC);

    float r0, r1, r2, r3;
    r0  = __uint_as_float(q00.x << 16)         * w00;
    r1  = __uint_as_float(q00.x & 0xffff0000u) * w00;
    r2  = __uint_as_float(q00.y << 16)         * w00;
    r3  = __uint_as_float(q00.y & 0xffff0000u) * w00;
    r0 += __uint_as_float(q10.x << 16)         * w10;
    r1 += __uint_as_float(q10.x & 0xffff0000u) * w10;
    r2 += __uint_as_float(q10.y << 16)         * w10;
    r3 += __uint_as_float(q10.y & 0xffff0000u) * w10;
    r0 += __uint_as_float(q01.x << 16)         * w01;
    r1 += __uint_as_float(q01.x & 0xffff0000u) * w01;
    r2 += __uint_as_float(q01.y << 16)         * w01;
    r3 += __uint_as_float(q01.y & 0xffff0000u) * w01;
    r0 += __uint_as_float(q11.x << 16)         * w11;
    r1 += __uint_as_float(q11.x & 0xffff0000u) * w11;
    r2 += __uint_as_float(q11.y << 16)         * w11;
    r3 += __uint_as_float(q11.y & 0xffff0000u) * w11;

    uint2 o;
    o.x = (unsigned)f2bf(r0) | ((unsigned)f2bf(r1) << 16);
    o.y = (unsigned)f2bf(r2) | ((unsigned)f2bf(r3) << 16);
    *(uint2*)(orow + l * MIDC) = o;
  }
}

// ============== fused GEMM (bf16 MFMA, K=448) + bias + relu ================
__global__ __launch_bounds__(256) void gemm_mfma_kernel(
    const u16*  __restrict__ Aimg,   // [100096][384] bf16 (rows>=100000 junk)
    const float* __restrict__ Apts,  // [100000][64] fp32
    const u16*  __restrict__ wg,     // frag-packed [14][128][4][8]
    const float* __restrict__ bias,
    float* __restrict__ outp)        // [100000][128]
{
  const int t = threadIdx.x, l = t & 63, wv = t >> 6;
  const int wm = wv >> 1, wn = wv & 1;
  const int lr = l & 15, lk = l >> 4;
  const int row0 = blockIdx.x * 64;

  f32x4 acc[2][4] = {};
  const u16* __restrict__ bln = wg + ((wn * 64 + lr) * 4 + lk) * 8;

  size_t ab[2];
  #pragma unroll
  for (int ag = 0; ag < 2; ++ag)
    ab[ag] = (size_t)(row0 + (wm * 2 + ag) * 16 + lr) * KIMG + lk * 8;

  #pragma unroll 4
  for (int ks = 0; ks < 12; ++ks) {
    bf16x8 A0 = *(const bf16x8*)(Aimg + ab[0] + ks * 32);
    bf16x8 A1 = *(const bf16x8*)(Aimg + ab[1] + ks * 32);
    const u16* __restrict__ bk = bln + ks * 4096;
    bf16x8 B0 = *(const bf16x8*)(bk);
    bf16x8 B1 = *(const bf16x8*)(bk + 512);
    bf16x8 B2 = *(const bf16x8*)(bk + 1024);
    bf16x8 B3 = *(const bf16x8*)(bk + 1536);
    acc[0][0] = __builtin_amdgcn_mfma_f32_16x16x32_bf16(A0, B0, acc[0][0], 0, 0, 0);
    acc[0][1] = __builtin_amdgcn_mfma_f32_16x16x32_bf16(A0, B1, acc[0][1], 0, 0, 0);
    acc[0][2] = __builtin_amdgcn_mfma_f32_16x16x32_bf16(A0, B2, acc[0][2], 0, 0, 0);
    acc[0][3] = __builtin_amdgcn_mfma_f32_16x16x32_bf16(A0, B3, acc[0][3], 0, 0, 0);
    acc[1][0] = __builtin_amdgcn_mfma_f32_16x16x32_bf16(A1, B0, acc[1][0], 0, 0, 0);
    acc[1][1] = __builtin_amdgcn_mfma_f32_16x16x32_bf16(A1, B1, acc[1][1], 0, 0, 0);
    acc[1][2] = __builtin_amdgcn_mfma_f32_16x16x32_bf16(A1, B2, acc[1][2], 0, 0, 0);
    acc[1][3] = __builtin_amdgcn_mfma_f32_16x16x32_bf16(A1, B3, acc[1][3], 0, 0, 0);
  }

  // pts tail (k 384..447): fp32 -> bf16 in-register
  int prow[2];
  #pragma unroll
  for (int ag = 0; ag < 2; ++ag)
    prow[ag] = min(row0 + (wm * 2 + ag) * 16 + lr, TOTPTS - 1);
  #pragma unroll
  for (int ks = 12; ks < 14; ++ks) {
    const int k0 = (ks - 12) * 32 + lk * 8;
    const float* __restrict__ p0 = Apts + (size_t)prow[0] * PTSC + k0;
    const float* __restrict__ p1 = Apts + (size_t)prow[1] * PTSC + k0;
    bf16x8 A0, A1;
    #pragma unroll
    for (int j = 0; j < 8; ++j) {
      A0[j] = (short)f2bf(p0[j]);
      A1[j] = (short)f2bf(p1[j]);
    }
    const u16* __restrict__ bk = bln + ks * 4096;
    bf16x8 B0 = *(const bf16x8*)(bk);
    bf16x8 B1 = *(const bf16x8*)(bk + 512);
    bf16x8 B2 = *(const bf16x8*)(bk + 1024);
    bf16x8 B3 = *(const bf16x8*)(bk + 1536);
    acc[0][0] = __builtin_amdgcn_mfma_f32_16x16x32_bf16(A0, B0, acc[0][0], 0, 0, 0);
    acc[0][1] = __builtin_amdgcn_mfma_f32_16x16x32_bf16(A0, B1, acc[0][1], 0, 0, 0);
    acc[0][2] = __builtin_amdgcn_mfma_f32_16x16x32_bf16(A0, B2, acc[0][2], 0, 0, 0);
    acc[0][3] = __builtin_amdgcn_mfma_f32_16x16x32_bf16(A0, B3, acc[0][3], 0, 0, 0);
    acc[1][0] = __builtin_amdgcn_mfma_f32_16x16x32_bf16(A1, B0, acc[1][0], 0, 0, 0);
    acc[1][1] = __builtin_amdgcn_mfma_f32_16x16x32_bf16(A1, B1, acc[1][1], 0, 0, 0);
    acc[1][2] = __builtin_amdgcn_mfma_f32_16x16x32_bf16(A1, B2, acc[1][2], 0, 0, 0);
    acc[1][3] = __builtin_amdgcn_mfma_f32_16x16x32_bf16(A1, B3, acc[1][3], 0, 0, 0);
  }

  #pragma unroll
  for (int ag = 0; ag < 2; ++ag) {
    #pragma unroll
    for (int rr = 0; rr < 4; ++rr) {
      const int row = row0 + (wm * 2 + ag) * 16 + lk * 4 + rr;
      if (row < TOTPTS) {
        float* __restrict__ po = outp + (size_t)row * OUTC;
        #pragma unroll
        for (int nf = 0; nf < 4; ++nf) {
          const int col = wn * 64 + nf * 16 + lr;
          po[col] = fmaxf(acc[ag][nf][rr] + bias[col], 0.f);
        }
      }
    }
  }
}

// ================================= host ====================================
extern "C" void kernel_launch(void* const* d_in, const int* in_sizes, int n_in,
                              void* d_out, int out_size, void* d_ws, size_t ws_size,
                              hipStream_t stream) {
  const float* f0_in  = (const float*)d_in[0];
  const float* f1_in  = (const float*)d_in[1];
  const float* f2_in  = (const float*)d_in[2];
  const float* pts    = (const float*)d_in[3];
  const float* ptsf   = (const float*)d_in[4];
  const float* l2i    = (const float*)d_in[5];
  const float* rot    = (const float*)d_in[6];
  const float* trans  = (const float*)d_in[7];
  const float* lat_w  = (const float*)d_in[8];
  const float* lat_b  = (const float*)d_in[9];
  const float* img_w  = (const float*)d_in[10];
  const float* img_b  = (const float*)d_in[11];
  const float* pts_w  = (const float*)d_in[12];
  const float* pts_b  = (const float*)d_in[13];
  const float* ibg    = (const float*)d_in[14];
  const float* ibbv   = (const float*)d_in[15];
  const float* ibm    = (const float*)d_in[16];
  const float* ibv    = (const float*)d_in[17];
  const float* pbg    = (const float*)d_in[18];
  const float* pbbv   = (const float*)d_in[19];
  const float* pbm    = (const float*)d_in[20];
  const float* pbv    = (const float*)d_in[21];
  float* outp = (float*)d_out;

  uint8_t* ws = (uint8_t*)d_ws;
  // persistent region
  const size_t off_wc   = 0;                        // 3*294912 bf16 = 1,769,472 B
  const size_t off_wg   = 1769472;                  // 57344 bf16    = 114,688 B
  const size_t off_bias = 1884160;                  // 128 f32
  const size_t off_c0   = 1884672;                  // 3,932,160 B
  const size_t off_c1   = off_c0 + 3932160;
  const size_t off_c2   = off_c1 + 983040;
  const size_t off_big  = off_c2 + 245760;          // = 7,045,632
  // transient: padded inputs live at off_big, overwritten later by img_pts
  const size_t p0_off = 0;                          // elems within big
  const size_t p1_off = 4147200;
  const size_t p2_off = 5238784;                    // end 5,539,840 elems
  // img_pts also at off_big (100096 rows * 384 bf16 = 76,873,728 B)

  u16*   wc   = (u16*)(ws + off_wc);
  u16*   wg   = (u16*)(ws + off_wg);
  float* bias = (float*)(ws + off_bias);
  u16*   c0   = (u16*)(ws + off_c0);
  u16*   cbuf = c0;
  u16*   c1   = (u16*)(ws + off_c1);
  u16*   c2   = (u16*)(ws + off_c2);
  u16*   big  = (u16*)(ws + off_big);
  u16*   imgp = big;

  // 1) zero padded region (+16 KB slack for edge-tile overreads)
  zero_kernel<<<1024, 256, 0, stream>>>((uint4*)big, (5539840 * 2 + 16384) / 16);

  // 2) NCHW f32 -> padded NHWC bf16
  nchw2nhwc_kernel<<<dim3(5, 48, 8), 256, 0, stream>>>(f0_in, big + p0_off, 48, 160);
  nchw2nhwc_kernel<<<dim3(3, 24, 8), 256, 0, stream>>>(f1_in, big + p1_off, 24, 80);
  nchw2nhwc_kernel<<<dim3(2, 12, 8), 256, 0, stream>>>(f2_in, big + p2_off, 12, 40);

  // 3) weight prep
  prep_kernel<<<3680, 256, 0, stream>>>(
      img_w, img_b, pts_w, pts_b, ibg, ibbv, ibm, ibv,
      pbg, pbbv, pbm, pbv, lat_w, wg, wc, bias);

  // 4) conv, all levels in one dispatch
  ConvParams P;
  P.base[0] = 0; P.base[1] = 240; P.base[2] = 300; P.base[3] = 318;
  P.H[0] = 48;  P.H[1] = 24; P.H[2] = 12;
  P.W[0] = 160; P.W[1] = 80; P.W[2] = 40;
  P.tx[0] = 10; P.tx[1] = 5;  P.tx[2] = 3;
  P.poff[0] = (int)p0_off; P.poff[1] = (int)p1_off; P.poff[2] = (int)p2_off;
  P.coff[0] = 0; P.coff[1] = 1966080; P.coff[2] = 2457600;
  P.woff[0] = 0; P.woff[1] = 294912;  P.woff[2] = 589824;
  conv_mfma_kernel<<<318, 256, 0, stream>>>(big, wc, lat_b, cbuf, P);

  // 5) sampling (reads conv outs, writes img_pts over the dead padded region)
  sample_kernel<<<TOTPTS / 8, 256, 0, stream>>>(
      pts, l2i, rot, trans, c0, c1, c2, imgp);

  // 6) fused GEMM + bias + BN + relu
  gemm_mfma_kernel<<<(TOTPTS + 63) / 64, 256, 0, stream>>>(
      imgp, ptsf, wg, bias, outp);

  (void)in_sizes; (void)n_in; (void)out_size; (void)ws_size;
}

// Round 6
// 157.414 us; speedup vs baseline: 7.3803x; 1.0055x over previous
//
#include <hip/hip_runtime.h>
#include <stdint.h>

using u16 = unsigned short;
typedef __attribute__((ext_vector_type(8))) short bf16x8;
typedef __attribute__((ext_vector_type(4))) float f32x4;

#define DEVI static __device__ __forceinline__

constexpr int BATCH  = 2;
constexpr int NPTS   = 50000;
constexpr int TOTPTS = BATCH * NPTS;      // 100000
constexpr int CIMG   = 256;
constexpr int MIDC   = 128;
constexpr int OUTC   = 128;
constexpr int PTSC   = 64;
constexpr int KIMG   = 384;               // 3 * 128
constexpr int KTOT   = 448;
constexpr float WPADf = 1280.f, HPADf = 384.f;
constexpr float BNEPS = 1e-3f;

DEVI u16 f2bf(float f) {                  // RNE float -> bf16 bits
  unsigned x = __float_as_uint(f);
  return (u16)((x + 0x7fffu + ((x >> 16) & 1u)) >> 16);
}
DEVI float bf2f(u16 u) { return __uint_as_float(((unsigned)u) << 16); }

// ============================ zero padded bufs =============================
__global__ __launch_bounds__(256) void zero_kernel(uint4* __restrict__ p, int n16) {
  int i = blockIdx.x * 256 + threadIdx.x;
  int stride = gridDim.x * 256;
  for (; i < n16; i += stride) p[i] = uint4{0u, 0u, 0u, 0u};
}

// ================= NCHW fp32 -> padded NHWC bf16 (per level) ===============
__global__ __launch_bounds__(256) void nchw2nhwc_kernel(
    const float* __restrict__ in, u16* __restrict__ outp, int H, int W) {
  __shared__ float s[64][33];
  const int t  = threadIdx.x;
  const int x0 = blockIdx.x * 32;
  const int y  = blockIdx.y;
  const int b  = blockIdx.z >> 2;
  const int c0 = (blockIdx.z & 3) * 64;
  #pragma unroll
  for (int i = 0; i < 8; ++i) {
    int e = t + i * 256, ci = e >> 5, xi = e & 31;
    float v = 0.f;
    if (x0 + xi < W) v = in[((size_t)(b * CIMG + c0 + ci) * H + y) * W + x0 + xi];
    s[ci][xi] = v;
  }
  __syncthreads();
  const int Wp = W + 2;
  #pragma unroll
  for (int i = 0; i < 8; ++i) {
    int e = t + i * 256, xi = e >> 6, ci = e & 63;
    if (x0 + xi < W)
      outp[((size_t)(b * (H + 2) + y + 1) * Wp + x0 + xi + 1) * CIMG + c0 + ci] =
          f2bf(s[ci][xi]);
  }
}

// ====== prep: BN-fold + bf16 frag-pack of GEMM & conv weights + bias =======
// pack layout: [ks][col(128)][s(4)][j(8)]  (k = ks*32 + s*8 + j)
__global__ __launch_bounds__(256) void prep_kernel(
    const float* __restrict__ img_w, const float* __restrict__ img_b,
    const float* __restrict__ pts_w, const float* __restrict__ pts_b,
    const float* __restrict__ ibg, const float* __restrict__ ibb,
    const float* __restrict__ ibm, const float* __restrict__ ibv,
    const float* __restrict__ pbg, const float* __restrict__ pbb,
    const float* __restrict__ pbm, const float* __restrict__ pbv,
    const float* __restrict__ lat_w,
    u16* __restrict__ wg, u16* __restrict__ wc, float* __restrict__ bias)
{
  int e = blockIdx.x * 256 + threadIdx.x;
  if (e < 57344) {                                   // GEMM pack 14*128*32
    int j = e & 7, s = (e >> 3) & 3, c = (e >> 5) & 127, ks = e >> 12;
    int k = ks * 32 + s * 8 + j;
    float s1 = ibg[c] * rsqrtf(ibv[c] + BNEPS);
    float s2 = pbg[c] * rsqrtf(pbv[c] + BNEPS);
    float w = (k < KIMG) ? img_w[c * KIMG + k] * s1
                         : pts_w[c * PTSC + (k - KIMG)] * s2;
    wg[e] = f2bf(w);
    if (e < OUTC) {
      float t1 = ibg[e] * rsqrtf(ibv[e] + BNEPS);
      float t2 = pbg[e] * rsqrtf(pbv[e] + BNEPS);
      bias[e] = (img_b[e] - ibm[e]) * t1 + ibb[e] +
                (pts_b[e] - pbm[e]) * t2 + pbb[e];
    }
  } else if (e < 57344 + 3 * 294912) {               // conv pack 3*72*128*32
    int q = e - 57344;
    int l = q / 294912, r = q % 294912;
    int j = r & 7, s = (r >> 3) & 3, c = (r >> 5) & 127, ks = r >> 12;
    int k = ks * 32 + s * 8 + j;                     // 0..2303
    int tap = k >> 8, ic = k & 255;
    float w = lat_w[(((size_t)l * 128 + c) * 256 + ic) * 9 + tap];
    wc[(size_t)l * 294912 + r] = f2bf(w);
  }
}

// =================== conv as implicit-GEMM MFMA (all levels) ===============
// LDS-staged A (6x18x256 bf16, swizzled), register-ring prefetched B.
struct ConvParams {
  int base[4];          // block-id level boundaries
  int H[3], W[3], tx[3];
  int poff[3];          // padded-input offsets (elements)
  int coff[3];          // conv-out offsets (elements)
  int woff[3];          // weight-pack offsets (elements)
};

__global__ __launch_bounds__(256, 2) void conv_mfma_kernel(
    const u16* __restrict__ pad, const u16* __restrict__ wc,
    const float* __restrict__ lat_b, u16* __restrict__ outbuf, ConvParams P)
{
  __shared__ u16 sA[6 * 18 * 256];                  // 55,296 B
  const int bid = blockIdx.x;
  const int lvl = (bid >= P.base[1]) + (bid >= P.base[2]);
  const int local = bid - P.base[lvl];
  const int H = P.H[lvl], W = P.W[lvl], tilesx = P.tx[lvl];
  const int nxy = tilesx * (H >> 2);
  const int b = local / nxy;
  const int r = local % nxy;
  const int ty = r / tilesx, tx = r - ty * tilesx;
  const int y0 = ty * 4, x0 = tx * 16;
  const int Wp = W + 2;
  const u16* __restrict__ pin = pad + P.poff[lvl];
  const u16* __restrict__ wl  = wc + P.woff[lvl];
  u16* __restrict__ outp = outbuf + P.coff[lvl];

  const int t = threadIdx.x, l = t & 63, wv = t >> 6;
  const int wm = wv >> 1, wn = wv & 1;
  const int lr = l & 15, lk = l >> 4;

  // ---- stage A tile: rows y0..y0+5 (padded idx), px x0..x0+17, 256 ch ----
  // LDS[(row*18+px)*512 + (bo ^ ((px&7)<<4))] = global[row][x0+px][bo]
  {
    const int pxi = l >> 5;                  // 0/1: px within 1KB chunk
    const int bo  = (l & 31) * 16;           // byte within 512B px block
    #pragma unroll
    for (int it = 0; it < 14; ++it) {
      const int ch = wv + it * 4;            // chunk 0..53 (1KB = 2 px)
      if (ch < 54) {
        const int rr2 = ch / 9;
        const int pp  = (ch % 9) * 2;
        const int px  = pp + pxi;
        const u16* src = pin +
            (((size_t)(b * (H + 2) + y0 + rr2) * Wp) + x0 + px) * CIMG + (bo >> 1);
        uint4 v = *(const uint4*)src;
        *(uint4*)((char*)sA + ch * 1024 + pxi * 512 + (bo ^ ((px & 7) << 4))) = v;
      }
    }
  }
  __syncthreads();

  f32x4 acc[2][4] = {};
  bf16x8 Ab[2][2], Bb[4][4];
  const u16* __restrict__ bln = wl + ((wn * 64 + lr) * 4 + lk) * 8;

  auto loadB = [&](int ks) {
    const u16* __restrict__ bk = bln + (size_t)ks * 4096;
    Bb[ks & 3][0] = *(const bf16x8*)(bk);
    Bb[ks & 3][1] = *(const bf16x8*)(bk + 512);
    Bb[ks & 3][2] = *(const bf16x8*)(bk + 1024);
    Bb[ks & 3][3] = *(const bf16x8*)(bk + 1536);
  };
  auto loadA = [&](int ks) {
    const int tap = ks >> 3, icc = ks & 7;
    const int ky = tap / 3, kx = tap - ky * 3;
    const int px = lr + kx;
    const int swz = (px & 7) << 4;
    #pragma unroll
    for (int ag = 0; ag < 2; ++ag) {
      const int row = wm * 2 + ag + ky;
      const int ba = (row * 18 + px) * 512 + ((icc * 64 + lk * 16) ^ swz);
      Ab[ks & 1][ag] = *(const bf16x8*)((const char*)sA + ba);
    }
  };

  loadB(0); loadB(1); loadB(2); loadB(3);
  loadA(0);
  #pragma unroll
  for (int ks = 0; ks < 72; ++ks) {
    if (ks < 71) loadA(ks + 1);
    const bf16x8 A0 = Ab[ks & 1][0], A1 = Ab[ks & 1][1];
    const bf16x8 B0 = Bb[ks & 3][0], B1 = Bb[ks & 3][1];
    const bf16x8 B2 = Bb[ks & 3][2], B3 = Bb[ks & 3][3];
    acc[0][0] = __builtin_amdgcn_mfma_f32_16x16x32_bf16(A0, B0, acc[0][0], 0, 0, 0);
    acc[0][1] = __builtin_amdgcn_mfma_f32_16x16x32_bf16(A0, B1, acc[0][1], 0, 0, 0);
    acc[0][2] = __builtin_amdgcn_mfma_f32_16x16x32_bf16(A0, B2, acc[0][2], 0, 0, 0);
    acc[0][3] = __builtin_amdgcn_mfma_f32_16x16x32_bf16(A0, B3, acc[0][3], 0, 0, 0);
    acc[1][0] = __builtin_amdgcn_mfma_f32_16x16x32_bf16(A1, B0, acc[1][0], 0, 0, 0);
    acc[1][1] = __builtin_amdgcn_mfma_f32_16x16x32_bf16(A1, B1, acc[1][1], 0, 0, 0);
    acc[1][2] = __builtin_amdgcn_mfma_f32_16x16x32_bf16(A1, B2, acc[1][2], 0, 0, 0);
    acc[1][3] = __builtin_amdgcn_mfma_f32_16x16x32_bf16(A1, B3, acc[1][3], 0, 0, 0);
    if (ks + 4 < 72) loadB(ks + 4);
  }

  const int ocb = wn * 64;
  #pragma unroll
  for (int ag = 0; ag < 2; ++ag) {
    const int y = y0 + wm * 2 + ag;
    #pragma unroll
    for (int rr = 0; rr < 4; ++rr) {
      const int x = x0 + lk * 4 + rr;
      if (x < W) {
        const size_t o = ((size_t)(b * H + y) * W + x) * MIDC;
        #pragma unroll
        for (int nf = 0; nf < 4; ++nf) {
          const int oc = ocb + nf * 16 + lr;
          outp[o + oc] = f2bf(acc[ag][nf][rr] + lat_b[lvl * 128 + oc]);
        }
      }
    }
  }
}

// ===== projection + bilinear sampling -> img_pts (4 ch/lane, branchless) ===
__global__ __launch_bounds__(256) void sample_kernel(
    const float* __restrict__ pts, const float* __restrict__ l2i,
    const float* __restrict__ rot, const float* __restrict__ trans,
    const u16* __restrict__ f0, const u16* __restrict__ f1,
    const u16* __restrict__ f2, u16* __restrict__ img_pts)
{
  const int t  = threadIdx.x;
  const int lq = t & 31;                   // channel quad 0..31 (ch = lq*4..lq*4+3)
  const int pt = blockIdx.x * 8 + (t >> 5);
  const int b  = pt / NPTS;

  const float* P = pts + (size_t)pt * 3;
  const float* T = trans + b * 3;
  const float* R = rot + b * 9;
  const float* L = l2i + b * 16;
  float dx = P[0] - T[0], dy = P[1] - T[1], dz = P[2] - T[2];
  float p0 = dx * R[0] + dy * R[1] + dz * R[2];
  float p1 = dx * R[3] + dy * R[4] + dz * R[5];
  float p2 = dx * R[6] + dy * R[7] + dz * R[8];
  float pc0 = L[0] * p0 + L[1] * p1 + L[2]  * p2 + L[3];
  float pc1 = L[4] * p0 + L[5] * p1 + L[6]  * p2 + L[7];
  float pc2 = L[8] * p0 + L[9] * p1 + L[10] * p2 + L[11];
  float z  = fmaxf(pc2, 1e-5f);
  float gx = pc0 / z / WPADf * 2.f - 1.f;
  float gy = pc1 / z / HPADf * 2.f - 1.f;

  const u16* __restrict__ feats[3] = {f0, f1, f2};
  const int Hs[3] = {48, 24, 12}, Ws[3] = {160, 80, 40};
  u16* __restrict__ orow = img_pts + (size_t)pt * KIMG + lq * 4;

  #pragma unroll
  for (int l = 0; l < 3; ++l) {
    const int Hl = Hs[l], Wl = Ws[l];
    const float Wm1 = (float)(Wl - 1), Hm1 = (float)(Hl - 1);
    float ix = (gx + 1.f) * 0.5f * Wm1;
    float iy = (gy + 1.f) * 0.5f * Hm1;
    float xf = floorf(ix), yf = floorf(iy);
    float wx1 = ix - xf, wy1 = iy - yf;
    float wx0 = 1.f - wx1, wy0 = 1.f - wy1;
    // validity folded into weights (reference: clip index, zero invalid taps)
    float ax0 = (xf >= 0.f        && xf <= Wm1)        ? wx0 : 0.f;
    float ax1 = (xf + 1.f >= 0.f  && xf + 1.f <= Wm1)  ? wx1 : 0.f;
    float ay0 = (yf >= 0.f        && yf <= Hm1)        ? wy0 : 0.f;
    float ay1 = (yf + 1.f >= 0.f  && yf + 1.f <= Hm1)  ? wy1 : 0.f;
    float w00 = ax0 * ay0, w10 = ax1 * ay0, w01 = ax0 * ay1, w11 = ax1 * ay1;
    // clamped integer indices (always-in-bounds addresses)
    int xi0 = (int)fminf(fmaxf(xf,       0.f), Wm1);
    int xi1 = (int)fminf(fmaxf(xf + 1.f, 0.f), Wm1);
    int yi0 = (int)fminf(fmaxf(yf,       0.f), Hm1);
    int yi1 = (int)fminf(fmaxf(yf + 1.f, 0.f), Hm1);

    const u16* __restrict__ fb = feats[l] + ((size_t)b * Hl * Wl) * MIDC + lq * 4;
    uint2 q00 = *(const uint2*)(fb + (size_t)(yi0 * Wl + xi0) * MIDC);
    uint2 q10 = *(const uint2*)(fb + (size_t)(yi0 * Wl + xi1) * MIDC);
    uint2 q01 = *(const uint2*)(fb + (size_t)(yi1 * Wl + xi0) * MIDC);
    uint2 q11 = *(const uint2*)(fb + (size_t)(yi1 * Wl + xi1) * MIDC);

    float r0, r1, r2, r3;
    r0  = __uint_as_float(q00.x << 16)         * w00;
    r1  = __uint_as_float(q00.x & 0xffff0000u) * w00;
    r2  = __uint_as_float(q00.y << 16)         * w00;
    r3  = __uint_as_float(q00.y & 0xffff0000u) * w00;
    r0 += __uint_as_float(q10.x << 16)         * w10;
    r1 += __uint_as_float(q10.x & 0xffff0000u) * w10;
    r2 += __uint_as_float(q10.y << 16)         * w10;
    r3 += __uint_as_float(q10.y & 0xffff0000u) * w10;
    r0 += __uint_as_float(q01.x << 16)         * w01;
    r1 += __uint_as_float(q01.x & 0xffff0000u) * w01;
    r2 += __uint_as_float(q01.y << 16)         * w01;
    r3 += __uint_as_float(q01.y & 0xffff0000u) * w01;
    r0 += __uint_as_float(q11.x << 16)         * w11;
    r1 += __uint_as_float(q11.x & 0xffff0000u) * w11;
    r2 += __uint_as_float(q11.y << 16)         * w11;
    r3 += __uint_as_float(q11.y & 0xffff0000u) * w11;

    uint2 o;
    o.x = (unsigned)f2bf(r0) | ((unsigned)f2bf(r1) << 16);
    o.y = (unsigned)f2bf(r2) | ((unsigned)f2bf(r3) << 16);
    *(uint2*)(orow + l * MIDC) = o;
  }
}

// ============== fused GEMM (bf16 MFMA, K=448) + bias + relu ================
// Fully unrolled K-loop with explicit 4-deep register rings (A and B) and
// prologue-hoisted pts-tail f32 loads: keeps ~24KB/wave of loads in flight.
__global__ __launch_bounds__(256) void gemm_mfma_kernel(
    const u16*  __restrict__ Aimg,   // [100096][384] bf16 (rows>=100000 junk)
    const float* __restrict__ Apts,  // [100000][64] fp32
    const u16*  __restrict__ wg,     // frag-packed [14][128][4][8]
    const float* __restrict__ bias,
    float* __restrict__ outp)        // [100000][128]
{
  const int t = threadIdx.x, l = t & 63, wv = t >> 6;
  const int wm = wv >> 1, wn = wv & 1;
  const int lr = l & 15, lk = l >> 4;
  const int row0 = blockIdx.x * 64;

  f32x4 acc[2][4] = {};
  const u16* __restrict__ bln = wg + ((wn * 64 + lr) * 4 + lk) * 8;

  size_t ab[2];
  int prow[2];
  #pragma unroll
  for (int ag = 0; ag < 2; ++ag) {
    const int r = row0 + (wm * 2 + ag) * 16 + lr;
    ab[ag] = (size_t)r * KIMG + lk * 8;
    prow[ag] = min(r, TOTPTS - 1);
  }

  bf16x8 Ar[4][2];
  bf16x8 Br[4][4];
  float  Pr[2][2][8];                // raw f32 pts fragments, converted late

  // pts-tail loads first (deepest in flight, no convert-at-issue stall)
  #pragma unroll
  for (int s2 = 0; s2 < 2; ++s2)
    #pragma unroll
    for (int ag = 0; ag < 2; ++ag) {
      const float* __restrict__ p = Apts + (size_t)prow[ag] * PTSC + s2 * 32 + lk * 8;
      *(float4*)&Pr[s2][ag][0] = *(const float4*)(p);
      *(float4*)&Pr[s2][ag][4] = *(const float4*)(p + 4);
    }

  auto loadA = [&](int ks) {
    Ar[ks & 3][0] = *(const bf16x8*)(Aimg + ab[0] + ks * 32);
    Ar[ks & 3][1] = *(const bf16x8*)(Aimg + ab[1] + ks * 32);
  };
  auto loadB = [&](int ks) {
    const u16* __restrict__ bk = bln + (size_t)ks * 4096;
    Br[ks & 3][0] = *(const bf16x8*)(bk);
    Br[ks & 3][1] = *(const bf16x8*)(bk + 512);
    Br[ks & 3][2] = *(const bf16x8*)(bk + 1024);
    Br[ks & 3][3] = *(const bf16x8*)(bk + 1536);
  };

  loadA(0); loadA(1); loadA(2); loadA(3);
  loadB(0); loadB(1); loadB(2); loadB(3);

  #pragma unroll
  for (int ks = 0; ks < 14; ++ks) {
    bf16x8 A0, A1;
    if (ks < 12) {
      A0 = Ar[ks & 3][0];
      A1 = Ar[ks & 3][1];
    } else {
      #pragma unroll
      for (int j = 0; j < 8; ++j) {
        A0[j] = (short)f2bf(Pr[ks - 12][0][j]);
        A1[j] = (short)f2bf(Pr[ks - 12][1][j]);
      }
    }
    const bf16x8 B0 = Br[ks & 3][0], B1 = Br[ks & 3][1];
    const bf16x8 B2 = Br[ks & 3][2], B3 = Br[ks & 3][3];
    acc[0][0] = __builtin_amdgcn_mfma_f32_16x16x32_bf16(A0, B0, acc[0][0], 0, 0, 0);
    acc[0][1] = __builtin_amdgcn_mfma_f32_16x16x32_bf16(A0, B1, acc[0][1], 0, 0, 0);
    acc[0][2] = __builtin_amdgcn_mfma_f32_16x16x32_bf16(A0, B2, acc[0][2], 0, 0, 0);
    acc[0][3] = __builtin_amdgcn_mfma_f32_16x16x32_bf16(A0, B3, acc[0][3], 0, 0, 0);
    acc[1][0] = __builtin_amdgcn_mfma_f32_16x16x32_bf16(A1, B0, acc[1][0], 0, 0, 0);
    acc[1][1] = __builtin_amdgcn_mfma_f32_16x16x32_bf16(A1, B1, acc[1][1], 0, 0, 0);
    acc[1][2] = __builtin_amdgcn_mfma_f32_16x16x32_bf16(A1, B2, acc[1][2], 0, 0, 0);
    acc[1][3] = __builtin_amdgcn_mfma_f32_16x16x32_bf16(A1, B3, acc[1][3], 0, 0, 0);
    if (ks + 4 < 12) loadA(ks + 4);
    if (ks + 4 < 14) loadB(ks + 4);
  }

  #pragma unroll
  for (int ag = 0; ag < 2; ++ag) {
    #pragma unroll
    for (int rr = 0; rr < 4; ++rr) {
      const int row = row0 + (wm * 2 + ag) * 16 + lk * 4 + rr;
      if (row < TOTPTS) {
        float* __restrict__ po = outp + (size_t)row * OUTC;
        #pragma unroll
        for (int nf = 0; nf < 4; ++nf) {
          const int col = wn * 64 + nf * 16 + lr;
          po[col] = fmaxf(acc[ag][nf][rr] + bias[col], 0.f);
        }
      }
    }
  }
}

// ================================= host ====================================
extern "C" void kernel_launch(void* const* d_in, const int* in_sizes, int n_in,
                              void* d_out, int out_size, void* d_ws, size_t ws_size,
                              hipStream_t stream) {
  const float* f0_in  = (const float*)d_in[0];
  const float* f1_in  = (const float*)d_in[1];
  const float* f2_in  = (const float*)d_in[2];
  const float* pts    = (const float*)d_in[3];
  const float* ptsf   = (const float*)d_in[4];
  const float* l2i    = (const float*)d_in[5];
  const float* rot    = (const float*)d_in[6];
  const float* trans  = (const float*)d_in[7];
  const float* lat_w  = (const float*)d_in[8];
  const float* lat_b  = (const float*)d_in[9];
  const float* img_w  = (const float*)d_in[10];
  const float* img_b  = (const float*)d_in[11];
  const float* pts_w  = (const float*)d_in[12];
  const float* pts_b  = (const float*)d_in[13];
  const float* ibg    = (const float*)d_in[14];
  const float* ibbv   = (const float*)d_in[15];
  const float* ibm    = (const float*)d_in[16];
  const float* ibv    = (const float*)d_in[17];
  const float* pbg    = (const float*)d_in[18];
  const float* pbbv   = (const float*)d_in[19];
  const float* pbm    = (const float*)d_in[20];
  const float* pbv    = (const float*)d_in[21];
  float* outp = (float*)d_out;

  uint8_t* ws = (uint8_t*)d_ws;
  // persistent region
  const size_t off_wc   = 0;                        // 3*294912 bf16 = 1,769,472 B
  const size_t off_wg   = 1769472;                  // 57344 bf16    = 114,688 B
  const size_t off_bias = 1884160;                  // 128 f32
  const size_t off_c0   = 1884672;                  // 3,932,160 B
  const size_t off_c1   = off_c0 + 3932160;
  const size_t off_c2   = off_c1 + 983040;
  const size_t off_big  = off_c2 + 245760;          // = 7,045,632
  // transient: padded inputs live at off_big, overwritten later by img_pts
  const size_t p0_off = 0;                          // elems within big
  const size_t p1_off = 4147200;
  const size_t p2_off = 5238784;                    // end 5,539,840 elems
  // img_pts also at off_big (100096 rows * 384 bf16 = 76,873,728 B)

  u16*   wc   = (u16*)(ws + off_wc);
  u16*   wg   = (u16*)(ws + off_wg);
  float* bias = (float*)(ws + off_bias);
  u16*   c0   = (u16*)(ws + off_c0);
  u16*   cbuf = c0;
  u16*   c1   = (u16*)(ws + off_c1);
  u16*   c2   = (u16*)(ws + off_c2);
  u16*   big  = (u16*)(ws + off_big);
  u16*   imgp = big;

  // 1) zero padded region (+16 KB slack for edge-tile overreads)
  zero_kernel<<<1024, 256, 0, stream>>>((uint4*)big, (5539840 * 2 + 16384) / 16);

  // 2) NCHW f32 -> padded NHWC bf16
  nchw2nhwc_kernel<<<dim3(5, 48, 8), 256, 0, stream>>>(f0_in, big + p0_off, 48, 160);
  nchw2nhwc_kernel<<<dim3(3, 24, 8), 256, 0, stream>>>(f1_in, big + p1_off, 24, 80);
  nchw2nhwc_kernel<<<dim3(2, 12, 8), 256, 0, stream>>>(f2_in, big + p2_off, 12, 40);

  // 3) weight prep
  prep_kernel<<<3680, 256, 0, stream>>>(
      img_w, img_b, pts_w, pts_b, ibg, ibbv, ibm, ibv,
      pbg, pbbv, pbm, pbv, lat_w, wg, wc, bias);

  // 4) conv, all levels in one dispatch
  ConvParams P;
  P.base[0] = 0; P.base[1] = 240; P.base[2] = 300; P.base[3] = 318;
  P.H[0] = 48;  P.H[1] = 24; P.H[2] = 12;
  P.W[0] = 160; P.W[1] = 80; P.W[2] = 40;
  P.tx[0] = 10; P.tx[1] = 5;  P.tx[2] = 3;
  P.poff[0] = (int)p0_off; P.poff[1] = (int)p1_off; P.poff[2] = (int)p2_off;
  P.coff[0] = 0; P.coff[1] = 1966080; P.coff[2] = 2457600;
  P.woff[0] = 0; P.woff[1] = 294912;  P.woff[2] = 589824;
  conv_mfma_kernel<<<318, 256, 0, stream>>>(big, wc, lat_b, cbuf, P);

  // 5) sampling (reads conv outs, writes img_pts over the dead padded region)
  sample_kernel<<<TOTPTS / 8, 256, 0, stream>>>(
      pts, l2i, rot, trans, c0, c1, c2, imgp);

  // 6) fused GEMM + bias + BN + relu
  gemm_mfma_kernel<<<(TOTPTS + 63) / 64, 256, 0, stream>>>(
      imgp, ptsf, wg, bias, outp);

  (void)in_sizes; (void)n_in; (void)out_size; (void)ws_size;
}

// Round 7
// 147.424 us; speedup vs baseline: 7.8804x; 1.0678x over previous
//
#include <hip/hip_runtime.h>
#include <stdint.h>

using u16 = unsigned short;
typedef __attribute__((ext_vector_type(8))) short bf16x8;
typedef __attribute__((ext_vector_type(4))) float f32x4;

#define DEVI static __device__ __forceinline__

constexpr int BATCH  = 2;
constexpr int NPTS   = 50000;
constexpr int TOTPTS = BATCH * NPTS;      // 100000
constexpr int CIMG   = 256;
constexpr int MIDC   = 128;
constexpr int OUTC   = 128;
constexpr int PTSC   = 64;
constexpr int KIMG   = 384;               // 3 * 128
constexpr int KTOT   = 448;
constexpr float WPADf = 1280.f, HPADf = 384.f;
constexpr float BNEPS = 1e-3f;

DEVI u16 f2bf(float f) {                  // RNE float -> bf16 bits
  unsigned x = __float_as_uint(f);
  return (u16)((x + 0x7fffu + ((x >> 16) & 1u)) >> 16);
}
DEVI float bf2f(u16 u) { return __uint_as_float(((unsigned)u) << 16); }

// ============================ zero padded bufs =============================
__global__ __launch_bounds__(256) void zero_kernel(uint4* __restrict__ p, int n16) {
  int i = blockIdx.x * 256 + threadIdx.x;
  int stride = gridDim.x * 256;
  for (; i < n16; i += stride) p[i] = uint4{0u, 0u, 0u, 0u};
}

// ================= NCHW fp32 -> padded NHWC bf16 (per level) ===============
__global__ __launch_bounds__(256) void nchw2nhwc_kernel(
    const float* __restrict__ in, u16* __restrict__ outp, int H, int W) {
  __shared__ float s[64][33];
  const int t  = threadIdx.x;
  const int x0 = blockIdx.x * 32;
  const int y  = blockIdx.y;
  const int b  = blockIdx.z >> 2;
  const int c0 = (blockIdx.z & 3) * 64;
  #pragma unroll
  for (int i = 0; i < 8; ++i) {
    int e = t + i * 256, ci = e >> 5, xi = e & 31;
    float v = 0.f;
    if (x0 + xi < W) v = in[((size_t)(b * CIMG + c0 + ci) * H + y) * W + x0 + xi];
    s[ci][xi] = v;
  }
  __syncthreads();
  const int Wp = W + 2;
  #pragma unroll
  for (int i = 0; i < 8; ++i) {
    int e = t + i * 256, xi = e >> 6, ci = e & 63;
    if (x0 + xi < W)
      outp[((size_t)(b * (H + 2) + y + 1) * Wp + x0 + xi + 1) * CIMG + c0 + ci] =
          f2bf(s[ci][xi]);
  }
}

// ====== prep: BN-fold + bf16 frag-pack of GEMM & conv weights + bias =======
// pack layout: [ks][col(128)][s(4)][j(8)]  (k = ks*32 + s*8 + j)
__global__ __launch_bounds__(256) void prep_kernel(
    const float* __restrict__ img_w, const float* __restrict__ img_b,
    const float* __restrict__ pts_w, const float* __restrict__ pts_b,
    const float* __restrict__ ibg, const float* __restrict__ ibb,
    const float* __restrict__ ibm, const float* __restrict__ ibv,
    const float* __restrict__ pbg, const float* __restrict__ pbb,
    const float* __restrict__ pbm, const float* __restrict__ pbv,
    const float* __restrict__ lat_w,
    u16* __restrict__ wg, u16* __restrict__ wc, float* __restrict__ bias)
{
  int e = blockIdx.x * 256 + threadIdx.x;
  if (e < 57344) {                                   // GEMM pack 14*128*32
    int j = e & 7, s = (e >> 3) & 3, c = (e >> 5) & 127, ks = e >> 12;
    int k = ks * 32 + s * 8 + j;
    float s1 = ibg[c] * rsqrtf(ibv[c] + BNEPS);
    float s2 = pbg[c] * rsqrtf(pbv[c] + BNEPS);
    float w = (k < KIMG) ? img_w[c * KIMG + k] * s1
                         : pts_w[c * PTSC + (k - KIMG)] * s2;
    wg[e] = f2bf(w);
    if (e < OUTC) {
      float t1 = ibg[e] * rsqrtf(ibv[e] + BNEPS);
      float t2 = pbg[e] * rsqrtf(pbv[e] + BNEPS);
      bias[e] = (img_b[e] - ibm[e]) * t1 + ibb[e] +
                (pts_b[e] - pbm[e]) * t2 + pbb[e];
    }
  } else if (e < 57344 + 3 * 294912) {               // conv pack 3*72*128*32
    int q = e - 57344;
    int l = q / 294912, r = q % 294912;
    int j = r & 7, s = (r >> 3) & 3, c = (r >> 5) & 127, ks = r >> 12;
    int k = ks * 32 + s * 8 + j;                     // 0..2303
    int tap = k >> 8, ic = k & 255;
    float w = lat_w[(((size_t)l * 128 + c) * 256 + ic) * 9 + tap];
    wc[(size_t)l * 294912 + r] = f2bf(w);
  }
}

// =================== conv as implicit-GEMM MFMA (all levels) ===============
// LDS-staged A (6x18x256 bf16, swizzled), register-ring prefetched B.
struct ConvParams {
  int base[4];          // block-id level boundaries
  int H[3], W[3], tx[3];
  int poff[3];          // padded-input offsets (elements)
  int coff[3];          // conv-out offsets (elements)
  int woff[3];          // weight-pack offsets (elements)
};

__global__ __launch_bounds__(256, 2) void conv_mfma_kernel(
    const u16* __restrict__ pad, const u16* __restrict__ wc,
    const float* __restrict__ lat_b, u16* __restrict__ outbuf, ConvParams P)
{
  __shared__ u16 sA[6 * 18 * 256];                  // 55,296 B
  const int bid = blockIdx.x;
  const int lvl = (bid >= P.base[1]) + (bid >= P.base[2]);
  const int local = bid - P.base[lvl];
  const int H = P.H[lvl], W = P.W[lvl], tilesx = P.tx[lvl];
  const int nxy = tilesx * (H >> 2);
  const int b = local / nxy;
  const int r = local % nxy;
  const int ty = r / tilesx, tx = r - ty * tilesx;
  const int y0 = ty * 4, x0 = tx * 16;
  const int Wp = W + 2;
  const u16* __restrict__ pin = pad + P.poff[lvl];
  const u16* __restrict__ wl  = wc + P.woff[lvl];
  u16* __restrict__ outp = outbuf + P.coff[lvl];

  const int t = threadIdx.x, l = t & 63, wv = t >> 6;
  const int wm = wv >> 1, wn = wv & 1;
  const int lr = l & 15, lk = l >> 4;

  // ---- stage A tile: rows y0..y0+5 (padded idx), px x0..x0+17, 256 ch ----
  {
    const int pxi = l >> 5;                  // 0/1: px within 1KB chunk
    const int bo  = (l & 31) * 16;           // byte within 512B px block
    #pragma unroll
    for (int it = 0; it < 14; ++it) {
      const int ch = wv + it * 4;            // chunk 0..53 (1KB = 2 px)
      if (ch < 54) {
        const int rr2 = ch / 9;
        const int pp  = (ch % 9) * 2;
        const int px  = pp + pxi;
        const u16* src = pin +
            (((size_t)(b * (H + 2) + y0 + rr2) * Wp) + x0 + px) * CIMG + (bo >> 1);
        uint4 v = *(const uint4*)src;
        *(uint4*)((char*)sA + ch * 1024 + pxi * 512 + (bo ^ ((px & 7) << 4))) = v;
      }
    }
  }
  __syncthreads();

  f32x4 acc[2][4] = {};
  bf16x8 Ab[2][2], Bb[4][4];
  const u16* __restrict__ bln = wl + ((wn * 64 + lr) * 4 + lk) * 8;

  auto loadB = [&](int ks) {
    const u16* __restrict__ bk = bln + (size_t)ks * 4096;
    Bb[ks & 3][0] = *(const bf16x8*)(bk);
    Bb[ks & 3][1] = *(const bf16x8*)(bk + 512);
    Bb[ks & 3][2] = *(const bf16x8*)(bk + 1024);
    Bb[ks & 3][3] = *(const bf16x8*)(bk + 1536);
  };
  auto loadA = [&](int ks) {
    const int tap = ks >> 3, icc = ks & 7;
    const int ky = tap / 3, kx = tap - ky * 3;
    const int px = lr + kx;
    const int swz = (px & 7) << 4;
    #pragma unroll
    for (int ag = 0; ag < 2; ++ag) {
      const int row = wm * 2 + ag + ky;
      const int ba = (row * 18 + px) * 512 + ((icc * 64 + lk * 16) ^ swz);
      Ab[ks & 1][ag] = *(const bf16x8*)((const char*)sA + ba);
    }
  };

  loadB(0); loadB(1); loadB(2); loadB(3);
  loadA(0);
  #pragma unroll
  for (int ks = 0; ks < 72; ++ks) {
    if (ks < 71) loadA(ks + 1);
    const bf16x8 A0 = Ab[ks & 1][0], A1 = Ab[ks & 1][1];
    const bf16x8 B0 = Bb[ks & 3][0], B1 = Bb[ks & 3][1];
    const bf16x8 B2 = Bb[ks & 3][2], B3 = Bb[ks & 3][3];
    acc[0][0] = __builtin_amdgcn_mfma_f32_16x16x32_bf16(A0, B0, acc[0][0], 0, 0, 0);
    acc[0][1] = __builtin_amdgcn_mfma_f32_16x16x32_bf16(A0, B1, acc[0][1], 0, 0, 0);
    acc[0][2] = __builtin_amdgcn_mfma_f32_16x16x32_bf16(A0, B2, acc[0][2], 0, 0, 0);
    acc[0][3] = __builtin_amdgcn_mfma_f32_16x16x32_bf16(A0, B3, acc[0][3], 0, 0, 0);
    acc[1][0] = __builtin_amdgcn_mfma_f32_16x16x32_bf16(A1, B0, acc[1][0], 0, 0, 0);
    acc[1][1] = __builtin_amdgcn_mfma_f32_16x16x32_bf16(A1, B1, acc[1][1], 0, 0, 0);
    acc[1][2] = __builtin_amdgcn_mfma_f32_16x16x32_bf16(A1, B2, acc[1][2], 0, 0, 0);
    acc[1][3] = __builtin_amdgcn_mfma_f32_16x16x32_bf16(A1, B3, acc[1][3], 0, 0, 0);
    if (ks + 4 < 72) loadB(ks + 4);
  }

  const int ocb = wn * 64;
  #pragma unroll
  for (int ag = 0; ag < 2; ++ag) {
    const int y = y0 + wm * 2 + ag;
    #pragma unroll
    for (int rr = 0; rr < 4; ++rr) {
      const int x = x0 + lk * 4 + rr;
      if (x < W) {
        const size_t o = ((size_t)(b * H + y) * W + x) * MIDC;
        #pragma unroll
        for (int nf = 0; nf < 4; ++nf) {
          const int oc = ocb + nf * 16 + lr;
          outp[o + oc] = f2bf(acc[ag][nf][rr] + lat_b[lvl * 128 + oc]);
        }
      }
    }
  }
}

// ======== FUSED: projection+bilinear sample -> LDS -> GEMM+bias+relu ========
// Block = 64 points. Phase 1: 32 lanes/point sample 384 chans into swizzled
// LDS tile. Phase 2: MFMA GEMM reading A-frags from LDS, B/pts from regs.
__global__ __launch_bounds__(256, 2) void sample_gemm_kernel(
    const float* __restrict__ pts, const float* __restrict__ l2i,
    const float* __restrict__ rot, const float* __restrict__ trans,
    const u16* __restrict__ f0, const u16* __restrict__ f1,
    const u16* __restrict__ f2,
    const float* __restrict__ Apts,  // [100000][64] fp32
    const u16*  __restrict__ wg,     // frag-packed [14][128][4][8]
    const float* __restrict__ bias,
    float* __restrict__ outp)        // [100000][128]
{
  __shared__ u16 sA[64 * KIMG];      // 49,152 B; 16B slots, slot ^= (row&7)
  const int t = threadIdx.x;
  const int row0 = blockIdx.x * 64;
  const int l = t & 63, wv = t >> 6;
  const int wm = wv >> 1, wn = wv & 1;
  const int lr = l & 15, lk = l >> 4;

  // ---- phase 0: B-ring + pts-tail prefetch (independent of LDS) ----
  bf16x8 Br[4][4];
  const u16* __restrict__ bln = wg + ((wn * 64 + lr) * 4 + lk) * 8;
  auto loadB = [&](int ks) {
    const u16* __restrict__ bk = bln + (size_t)ks * 4096;
    Br[ks & 3][0] = *(const bf16x8*)(bk);
    Br[ks & 3][1] = *(const bf16x8*)(bk + 512);
    Br[ks & 3][2] = *(const bf16x8*)(bk + 1024);
    Br[ks & 3][3] = *(const bf16x8*)(bk + 1536);
  };
  loadB(0); loadB(1); loadB(2); loadB(3);

  int prow[2];
  #pragma unroll
  for (int ag = 0; ag < 2; ++ag)
    prow[ag] = min(row0 + (wm * 2 + ag) * 16 + lr, TOTPTS - 1);
  float Pr[2][2][8];
  #pragma unroll
  for (int s2 = 0; s2 < 2; ++s2)
    #pragma unroll
    for (int ag = 0; ag < 2; ++ag) {
      const float* __restrict__ p = Apts + (size_t)prow[ag] * PTSC + s2 * 32 + lk * 8;
      *(float4*)&Pr[s2][ag][0] = *(const float4*)(p);
      *(float4*)&Pr[s2][ag][4] = *(const float4*)(p + 4);
    }

  // ---- phase 1: sample 64 points into LDS ----
  {
    const int lq  = t & 31;
    const int grp = t >> 5;
    const u16* __restrict__ feats[3] = {f0, f1, f2};
    const int Hs[3] = {48, 24, 12}, Ws[3] = {160, 80, 40};
    #pragma unroll 2
    for (int it = 0; it < 8; ++it) {
      const int prw = it * 8 + grp;               // LDS row 0..63
      const int pt  = min(row0 + prw, TOTPTS - 1);
      const int b   = pt / NPTS;
      const float* P = pts + (size_t)pt * 3;
      const float* T = trans + b * 3;
      const float* R = rot + b * 9;
      const float* L = l2i + b * 16;
      float dx = P[0] - T[0], dy = P[1] - T[1], dz = P[2] - T[2];
      float p0 = dx * R[0] + dy * R[1] + dz * R[2];
      float p1 = dx * R[3] + dy * R[4] + dz * R[5];
      float p2 = dx * R[6] + dy * R[7] + dz * R[8];
      float pc0 = L[0] * p0 + L[1] * p1 + L[2]  * p2 + L[3];
      float pc1 = L[4] * p0 + L[5] * p1 + L[6]  * p2 + L[7];
      float pc2 = L[8] * p0 + L[9] * p1 + L[10] * p2 + L[11];
      float z  = fmaxf(pc2, 1e-5f);
      float gx = pc0 / z / WPADf * 2.f - 1.f;
      float gy = pc1 / z / HPADf * 2.f - 1.f;

      #pragma unroll
      for (int lv = 0; lv < 3; ++lv) {
        const int Hl = Hs[lv], Wl = Ws[lv];
        const float Wm1 = (float)(Wl - 1), Hm1 = (float)(Hl - 1);
        float ix = (gx + 1.f) * 0.5f * Wm1;
        float iy = (gy + 1.f) * 0.5f * Hm1;
        float xf = floorf(ix), yf = floorf(iy);
        float wx1 = ix - xf, wy1 = iy - yf;
        float wx0 = 1.f - wx1, wy0 = 1.f - wy1;
        float ax0 = (xf >= 0.f       && xf <= Wm1)       ? wx0 : 0.f;
        float ax1 = (xf + 1.f >= 0.f && xf + 1.f <= Wm1) ? wx1 : 0.f;
        float ay0 = (yf >= 0.f       && yf <= Hm1)       ? wy0 : 0.f;
        float ay1 = (yf + 1.f >= 0.f && yf + 1.f <= Hm1) ? wy1 : 0.f;
        float w00 = ax0 * ay0, w10 = ax1 * ay0, w01 = ax0 * ay1, w11 = ax1 * ay1;
        int xi0 = (int)fminf(fmaxf(xf,       0.f), Wm1);
        int xi1 = (int)fminf(fmaxf(xf + 1.f, 0.f), Wm1);
        int yi0 = (int)fminf(fmaxf(yf,       0.f), Hm1);
        int yi1 = (int)fminf(fmaxf(yf + 1.f, 0.f), Hm1);

        const u16* __restrict__ fb = feats[lv] + ((size_t)b * Hl * Wl) * MIDC + lq * 4;
        uint2 q00 = *(const uint2*)(fb + (size_t)(yi0 * Wl + xi0) * MIDC);
        uint2 q10 = *(const uint2*)(fb + (size_t)(yi0 * Wl + xi1) * MIDC);
        uint2 q01 = *(const uint2*)(fb + (size_t)(yi1 * Wl + xi0) * MIDC);
        uint2 q11 = *(const uint2*)(fb + (size_t)(yi1 * Wl + xi1) * MIDC);

        float r0, r1, r2, r3;
        r0  = __uint_as_float(q00.x << 16)         * w00;
        r1  = __uint_as_float(q00.x & 0xffff0000u) * w00;
        r2  = __uint_as_float(q00.y << 16)         * w00;
        r3  = __uint_as_float(q00.y & 0xffff0000u) * w00;
        r0 += __uint_as_float(q10.x << 16)         * w10;
        r1 += __uint_as_float(q10.x & 0xffff0000u) * w10;
        r2 += __uint_as_float(q10.y << 16)         * w10;
        r3 += __uint_as_float(q10.y & 0xffff0000u) * w10;
        r0 += __uint_as_float(q01.x << 16)         * w01;
        r1 += __uint_as_float(q01.x & 0xffff0000u) * w01;
        r2 += __uint_as_float(q01.y << 16)         * w01;
        r3 += __uint_as_float(q01.y & 0xffff0000u) * w01;
        r0 += __uint_as_float(q11.x << 16)         * w11;
        r1 += __uint_as_float(q11.x & 0xffff0000u) * w11;
        r2 += __uint_as_float(q11.y << 16)         * w11;
        r3 += __uint_as_float(q11.y & 0xffff0000u) * w11;

        uint2 o;
        o.x = (unsigned)f2bf(r0) | ((unsigned)f2bf(r1) << 16);
        o.y = (unsigned)f2bf(r2) | ((unsigned)f2bf(r3) << 16);
        const int slot = lv * 16 + (lq >> 1);
        const int addr = prw * 768 + ((slot ^ (prw & 7)) << 4) + (lq & 1) * 8;
        *(uint2*)((char*)sA + addr) = o;
      }
    }
  }
  __syncthreads();

  // ---- phase 2: GEMM from LDS A + reg B ----
  f32x4 acc[2][4] = {};
  bf16x8 Ab[2][2];
  auto loadA = [&](int ks) {
    #pragma unroll
    for (int ag = 0; ag < 2; ++ag) {
      const int r = (wm * 2 + ag) * 16 + lr;
      const int slot = ks * 4 + lk;
      const int addr = r * 768 + (((slot ^ (r & 7))) << 4);
      Ab[ks & 1][ag] = *(const bf16x8*)((const char*)sA + addr);
    }
  };
  loadA(0);

  #pragma unroll
  for (int ks = 0; ks < 14; ++ks) {
    if (ks + 1 < 12) loadA(ks + 1);
    bf16x8 A0, A1;
    if (ks < 12) {
      A0 = Ab[ks & 1][0];
      A1 = Ab[ks & 1][1];
    } else {
      #pragma unroll
      for (int j = 0; j < 8; ++j) {
        A0[j] = (short)f2bf(Pr[ks - 12][0][j]);
        A1[j] = (short)f2bf(Pr[ks - 12][1][j]);
      }
    }
    const bf16x8 B0 = Br[ks & 3][0], B1 = Br[ks & 3][1];
    const bf16x8 B2 = Br[ks & 3][2], B3 = Br[ks & 3][3];
    acc[0][0] = __builtin_amdgcn_mfma_f32_16x16x32_bf16(A0, B0, acc[0][0], 0, 0, 0);
    acc[0][1] = __builtin_amdgcn_mfma_f32_16x16x32_bf16(A0, B1, acc[0][1], 0, 0, 0);
    acc[0][2] = __builtin_amdgcn_mfma_f32_16x16x32_bf16(A0, B2, acc[0][2], 0, 0, 0);
    acc[0][3] = __builtin_amdgcn_mfma_f32_16x16x32_bf16(A0, B3, acc[0][3], 0, 0, 0);
    acc[1][0] = __builtin_amdgcn_mfma_f32_16x16x32_bf16(A1, B0, acc[1][0], 0, 0, 0);
    acc[1][1] = __builtin_amdgcn_mfma_f32_16x16x32_bf16(A1, B1, acc[1][1], 0, 0, 0);
    acc[1][2] = __builtin_amdgcn_mfma_f32_16x16x32_bf16(A1, B2, acc[1][2], 0, 0, 0);
    acc[1][3] = __builtin_amdgcn_mfma_f32_16x16x32_bf16(A1, B3, acc[1][3], 0, 0, 0);
    if (ks + 4 < 14) loadB(ks + 4);
  }

  #pragma unroll
  for (int ag = 0; ag < 2; ++ag) {
    #pragma unroll
    for (int rr = 0; rr < 4; ++rr) {
      const int row = row0 + (wm * 2 + ag) * 16 + lk * 4 + rr;
      if (row < TOTPTS) {
        float* __restrict__ po = outp + (size_t)row * OUTC;
        #pragma unroll
        for (int nf = 0; nf < 4; ++nf) {
          const int col = wn * 64 + nf * 16 + lr;
          po[col] = fmaxf(acc[ag][nf][rr] + bias[col], 0.f);
        }
      }
    }
  }
}

// ================================= host ====================================
extern "C" void kernel_launch(void* const* d_in, const int* in_sizes, int n_in,
                              void* d_out, int out_size, void* d_ws, size_t ws_size,
                              hipStream_t stream) {
  const float* f0_in  = (const float*)d_in[0];
  const float* f1_in  = (const float*)d_in[1];
  const float* f2_in  = (const float*)d_in[2];
  const float* pts    = (const float*)d_in[3];
  const float* ptsf   = (const float*)d_in[4];
  const float* l2i    = (const float*)d_in[5];
  const float* rot    = (const float*)d_in[6];
  const float* trans  = (const float*)d_in[7];
  const float* lat_w  = (const float*)d_in[8];
  const float* lat_b  = (const float*)d_in[9];
  const float* img_w  = (const float*)d_in[10];
  const float* img_b  = (const float*)d_in[11];
  const float* pts_w  = (const float*)d_in[12];
  const float* pts_b  = (const float*)d_in[13];
  const float* ibg    = (const float*)d_in[14];
  const float* ibbv   = (const float*)d_in[15];
  const float* ibm    = (const float*)d_in[16];
  const float* ibv    = (const float*)d_in[17];
  const float* pbg    = (const float*)d_in[18];
  const float* pbbv   = (const float*)d_in[19];
  const float* pbm    = (const float*)d_in[20];
  const float* pbv    = (const float*)d_in[21];
  float* outp = (float*)d_out;

  uint8_t* ws = (uint8_t*)d_ws;
  const size_t off_wc   = 0;                        // 3*294912 bf16
  const size_t off_wg   = 1769472;                  // 57344 bf16
  const size_t off_bias = 1884160;                  // 128 f32
  const size_t off_c0   = 1884672;
  const size_t off_c1   = off_c0 + 3932160;
  const size_t off_c2   = off_c1 + 983040;
  const size_t off_big  = off_c2 + 245760;          // padded conv inputs
  const size_t p0_off = 0;
  const size_t p1_off = 4147200;
  const size_t p2_off = 5238784;

  u16*   wc   = (u16*)(ws + off_wc);
  u16*   wg   = (u16*)(ws + off_wg);
  float* bias = (float*)(ws + off_bias);
  u16*   c0   = (u16*)(ws + off_c0);
  u16*   c1   = (u16*)(ws + off_c1);
  u16*   c2   = (u16*)(ws + off_c2);
  u16*   big  = (u16*)(ws + off_big);

  // 1) zero padded region (+16 KB slack for edge-tile overreads)
  zero_kernel<<<1024, 256, 0, stream>>>((uint4*)big, (5539840 * 2 + 16384) / 16);

  // 2) NCHW f32 -> padded NHWC bf16
  nchw2nhwc_kernel<<<dim3(5, 48, 8), 256, 0, stream>>>(f0_in, big + p0_off, 48, 160);
  nchw2nhwc_kernel<<<dim3(3, 24, 8), 256, 0, stream>>>(f1_in, big + p1_off, 24, 80);
  nchw2nhwc_kernel<<<dim3(2, 12, 8), 256, 0, stream>>>(f2_in, big + p2_off, 12, 40);

  // 3) weight prep
  prep_kernel<<<3680, 256, 0, stream>>>(
      img_w, img_b, pts_w, pts_b, ibg, ibbv, ibm, ibv,
      pbg, pbbv, pbm, pbv, lat_w, wg, wc, bias);

  // 4) conv, all levels in one dispatch
  ConvParams P;
  P.base[0] = 0; P.base[1] = 240; P.base[2] = 300; P.base[3] = 318;
  P.H[0] = 48;  P.H[1] = 24; P.H[2] = 12;
  P.W[0] = 160; P.W[1] = 80; P.W[2] = 40;
  P.tx[0] = 10; P.tx[1] = 5;  P.tx[2] = 3;
  P.poff[0] = (int)p0_off; P.poff[1] = (int)p1_off; P.poff[2] = (int)p2_off;
  P.coff[0] = 0; P.coff[1] = 1966080; P.coff[2] = 2457600;
  P.woff[0] = 0; P.woff[1] = 294912;  P.woff[2] = 589824;
  conv_mfma_kernel<<<318, 256, 0, stream>>>(big, wc, lat_b, c0, P);

  // 5) fused sample + GEMM + bias + BN + relu
  sample_gemm_kernel<<<(TOTPTS + 63) / 64, 256, 0, stream>>>(
      pts, l2i, rot, trans, c0, c1, c2, ptsf, wg, bias, outp);

  (void)in_sizes; (void)n_in; (void)out_size; (void)ws_size;
}

// Round 8
// 134.264 us; speedup vs baseline: 8.6528x; 1.0980x over previous
//
#include <hip/hip_runtime.h>
#include <stdint.h>

using u16 = unsigned short;
typedef __attribute__((ext_vector_type(8))) short bf16x8;
typedef __attribute__((ext_vector_type(4))) float f32x4;

#define DEVI static __device__ __forceinline__

constexpr int BATCH  = 2;
constexpr int NPTS   = 50000;
constexpr int TOTPTS = BATCH * NPTS;      // 100000
constexpr int CIMG   = 256;
constexpr int MIDC   = 128;
constexpr int OUTC   = 128;
constexpr int PTSC   = 64;
constexpr int KIMG   = 384;               // 3 * 128
constexpr int KTOT   = 448;
constexpr float WPADf = 1280.f, HPADf = 384.f;
constexpr float BNEPS = 1e-3f;

DEVI u16 f2bf(float f) {                  // RNE float -> bf16 bits
  unsigned x = __float_as_uint(f);
  return (u16)((x + 0x7fffu + ((x >> 16) & 1u)) >> 16);
}
DEVI float blo(unsigned u) { return __uint_as_float(u << 16); }
DEVI float bhi(unsigned u) { return __uint_as_float(u & 0xffff0000u); }

// ============================ zero padded bufs =============================
__global__ __launch_bounds__(256) void zero_kernel(uint4* __restrict__ p, int n16) {
  int i = blockIdx.x * 256 + threadIdx.x;
  int stride = gridDim.x * 256;
  for (; i < n16; i += stride) p[i] = uint4{0u, 0u, 0u, 0u};
}

// ================= NCHW fp32 -> padded NHWC bf16 (per level) ===============
__global__ __launch_bounds__(256) void nchw2nhwc_kernel(
    const float* __restrict__ in, u16* __restrict__ outp, int H, int W) {
  __shared__ float s[64][33];
  const int t  = threadIdx.x;
  const int x0 = blockIdx.x * 32;
  const int y  = blockIdx.y;
  const int b  = blockIdx.z >> 2;
  const int c0 = (blockIdx.z & 3) * 64;
  #pragma unroll
  for (int i = 0; i < 8; ++i) {
    int e = t + i * 256, ci = e >> 5, xi = e & 31;
    float v = 0.f;
    if (x0 + xi < W) v = in[((size_t)(b * CIMG + c0 + ci) * H + y) * W + x0 + xi];
    s[ci][xi] = v;
  }
  __syncthreads();
  const int Wp = W + 2;
  #pragma unroll
  for (int i = 0; i < 8; ++i) {
    int e = t + i * 256, xi = e >> 6, ci = e & 63;
    if (x0 + xi < W)
      outp[((size_t)(b * (H + 2) + y + 1) * Wp + x0 + xi + 1) * CIMG + c0 + ci] =
          f2bf(s[ci][xi]);
  }
}

// ====== prep: BN-fold + bf16 frag-pack of GEMM & conv weights + bias =======
__global__ __launch_bounds__(256) void prep_kernel(
    const float* __restrict__ img_w, const float* __restrict__ img_b,
    const float* __restrict__ pts_w, const float* __restrict__ pts_b,
    const float* __restrict__ ibg, const float* __restrict__ ibb,
    const float* __restrict__ ibm, const float* __restrict__ ibv,
    const float* __restrict__ pbg, const float* __restrict__ pbb,
    const float* __restrict__ pbm, const float* __restrict__ pbv,
    const float* __restrict__ lat_w,
    u16* __restrict__ wg, u16* __restrict__ wc, float* __restrict__ bias)
{
  int e = blockIdx.x * 256 + threadIdx.x;
  if (e < 57344) {                                   // GEMM pack 14*128*32
    int j = e & 7, s = (e >> 3) & 3, c = (e >> 5) & 127, ks = e >> 12;
    int k = ks * 32 + s * 8 + j;
    float s1 = ibg[c] * rsqrtf(ibv[c] + BNEPS);
    float s2 = pbg[c] * rsqrtf(pbv[c] + BNEPS);
    float w = (k < KIMG) ? img_w[c * KIMG + k] * s1
                         : pts_w[c * PTSC + (k - KIMG)] * s2;
    wg[e] = f2bf(w);
    if (e < OUTC) {
      float t1 = ibg[e] * rsqrtf(ibv[e] + BNEPS);
      float t2 = pbg[e] * rsqrtf(pbv[e] + BNEPS);
      bias[e] = (img_b[e] - ibm[e]) * t1 + ibb[e] +
                (pts_b[e] - pbm[e]) * t2 + pbb[e];
    }
  } else if (e < 57344 + 3 * 294912) {               // conv pack 3*72*128*32
    int q = e - 57344;
    int l = q / 294912, r = q % 294912;
    int j = r & 7, s = (r >> 3) & 3, c = (r >> 5) & 127, ks = r >> 12;
    int k = ks * 32 + s * 8 + j;                     // 0..2303
    int tap = k >> 8, ic = k & 255;
    float w = lat_w[(((size_t)l * 128 + c) * 256 + ic) * 9 + tap];
    wc[(size_t)l * 294912 + r] = f2bf(w);
  }
}

// =================== conv as implicit-GEMM MFMA (all levels) ===============
struct ConvParams {
  int base[4];
  int H[3], W[3], tx[3];
  int poff[3];
  int coff[3];
  int woff[3];
};

__global__ __launch_bounds__(256, 2) void conv_mfma_kernel(
    const u16* __restrict__ pad, const u16* __restrict__ wc,
    const float* __restrict__ lat_b, u16* __restrict__ outbuf, ConvParams P)
{
  __shared__ u16 sA[6 * 18 * 256];                  // 55,296 B
  const int bid = blockIdx.x;
  const int lvl = (bid >= P.base[1]) + (bid >= P.base[2]);
  const int local = bid - P.base[lvl];
  const int H = P.H[lvl], W = P.W[lvl], tilesx = P.tx[lvl];
  const int nxy = tilesx * (H >> 2);
  const int b = local / nxy;
  const int r = local % nxy;
  const int ty = r / tilesx, tx = r - ty * tilesx;
  const int y0 = ty * 4, x0 = tx * 16;
  const int Wp = W + 2;
  const u16* __restrict__ pin = pad + P.poff[lvl];
  const u16* __restrict__ wl  = wc + P.woff[lvl];
  u16* __restrict__ outp = outbuf + P.coff[lvl];

  const int t = threadIdx.x, l = t & 63, wv = t >> 6;
  const int wm = wv >> 1, wn = wv & 1;
  const int lr = l & 15, lk = l >> 4;

  {
    const int pxi = l >> 5;
    const int bo  = (l & 31) * 16;
    #pragma unroll
    for (int it = 0; it < 14; ++it) {
      const int ch = wv + it * 4;
      if (ch < 54) {
        const int rr2 = ch / 9;
        const int pp  = (ch % 9) * 2;
        const int px  = pp + pxi;
        const u16* src = pin +
            (((size_t)(b * (H + 2) + y0 + rr2) * Wp) + x0 + px) * CIMG + (bo >> 1);
        uint4 v = *(const uint4*)src;
        *(uint4*)((char*)sA + ch * 1024 + pxi * 512 + (bo ^ ((px & 7) << 4))) = v;
      }
    }
  }
  __syncthreads();

  f32x4 acc[2][4] = {};
  bf16x8 Ab[2][2], Bb[4][4];
  const u16* __restrict__ bln = wl + ((wn * 64 + lr) * 4 + lk) * 8;

  auto loadB = [&](int ks) {
    const u16* __restrict__ bk = bln + (size_t)ks * 4096;
    Bb[ks & 3][0] = *(const bf16x8*)(bk);
    Bb[ks & 3][1] = *(const bf16x8*)(bk + 512);
    Bb[ks & 3][2] = *(const bf16x8*)(bk + 1024);
    Bb[ks & 3][3] = *(const bf16x8*)(bk + 1536);
  };
  auto loadA = [&](int ks) {
    const int tap = ks >> 3, icc = ks & 7;
    const int ky = tap / 3, kx = tap - ky * 3;
    const int px = lr + kx;
    const int swz = (px & 7) << 4;
    #pragma unroll
    for (int ag = 0; ag < 2; ++ag) {
      const int row = wm * 2 + ag + ky;
      const int ba = (row * 18 + px) * 512 + ((icc * 64 + lk * 16) ^ swz);
      Ab[ks & 1][ag] = *(const bf16x8*)((const char*)sA + ba);
    }
  };

  loadB(0); loadB(1); loadB(2); loadB(3);
  loadA(0);
  #pragma unroll
  for (int ks = 0; ks < 72; ++ks) {
    if (ks < 71) loadA(ks + 1);
    const bf16x8 A0 = Ab[ks & 1][0], A1 = Ab[ks & 1][1];
    const bf16x8 B0 = Bb[ks & 3][0], B1 = Bb[ks & 3][1];
    const bf16x8 B2 = Bb[ks & 3][2], B3 = Bb[ks & 3][3];
    acc[0][0] = __builtin_amdgcn_mfma_f32_16x16x32_bf16(A0, B0, acc[0][0], 0, 0, 0);
    acc[0][1] = __builtin_amdgcn_mfma_f32_16x16x32_bf16(A0, B1, acc[0][1], 0, 0, 0);
    acc[0][2] = __builtin_amdgcn_mfma_f32_16x16x32_bf16(A0, B2, acc[0][2], 0, 0, 0);
    acc[0][3] = __builtin_amdgcn_mfma_f32_16x16x32_bf16(A0, B3, acc[0][3], 0, 0, 0);
    acc[1][0] = __builtin_amdgcn_mfma_f32_16x16x32_bf16(A1, B0, acc[1][0], 0, 0, 0);
    acc[1][1] = __builtin_amdgcn_mfma_f32_16x16x32_bf16(A1, B1, acc[1][1], 0, 0, 0);
    acc[1][2] = __builtin_amdgcn_mfma_f32_16x16x32_bf16(A1, B2, acc[1][2], 0, 0, 0);
    acc[1][3] = __builtin_amdgcn_mfma_f32_16x16x32_bf16(A1, B3, acc[1][3], 0, 0, 0);
    if (ks + 4 < 72) loadB(ks + 4);
  }

  const int ocb = wn * 64;
  #pragma unroll
  for (int ag = 0; ag < 2; ++ag) {
    const int y = y0 + wm * 2 + ag;
    #pragma unroll
    for (int rr = 0; rr < 4; ++rr) {
      const int x = x0 + lk * 4 + rr;
      if (x < W) {
        const size_t o = ((size_t)(b * H + y) * W + x) * MIDC;
        #pragma unroll
        for (int nf = 0; nf < 4; ++nf) {
          const int oc = ocb + nf * 16 + lr;
          outp[o + oc] = f2bf(acc[ag][nf][rr] + lat_b[lvl * 128 + oc]);
        }
      }
    }
  }
}

// ======== FUSED: params -> gather (16 lanes/pt, 8ch) -> GEMM (M=32) ========
__global__ __launch_bounds__(256, 4) void sample_gemm_kernel(
    const float* __restrict__ pts, const float* __restrict__ l2i,
    const float* __restrict__ rot, const float* __restrict__ trans,
    const u16* __restrict__ cbuf,    // conv outs (levels at fixed elem offsets)
    const float* __restrict__ Apts,  // [100000][64] fp32
    const u16*  __restrict__ wg,     // frag-packed [14][128][4][8]
    const float* __restrict__ bias,
    float* __restrict__ outp)        // [100000][128]
{
  __shared__ u16  sA[32 * KIMG];     // 24,576 B; 16B slots, slot ^= (row&7)
  __shared__ float sP[96 * 8];       // 3,072 B params [(lv*32+pt)*8]
  const int t = threadIdx.x;
  const int row0 = blockIdx.x * 32;
  const int l = t & 63, wv = t >> 6;
  const int rg = wv >> 1, wn = wv & 1;
  const int lr = l & 15, lk = l >> 4;

  // ---- phase 0: B-ring + pts-tail prefetch ----
  bf16x8 Br[4][4];
  const u16* __restrict__ bln = wg + ((wn * 64 + lr) * 4 + lk) * 8;
  auto loadB = [&](int ks) {
    const u16* __restrict__ bk = bln + (size_t)ks * 4096;
    Br[ks & 3][0] = *(const bf16x8*)(bk);
    Br[ks & 3][1] = *(const bf16x8*)(bk + 512);
    Br[ks & 3][2] = *(const bf16x8*)(bk + 1024);
    Br[ks & 3][3] = *(const bf16x8*)(bk + 1536);
  };
  loadB(0); loadB(1); loadB(2); loadB(3);

  const int myrow = row0 + rg * 16 + lr;      // always < TOTPTS (32 | 100000)
  float Pr[2][8];
  #pragma unroll
  for (int s2 = 0; s2 < 2; ++s2) {
    const float* __restrict__ p = Apts + (size_t)myrow * PTSC + s2 * 32 + lk * 8;
    *(float4*)&Pr[s2][0] = *(const float4*)(p);
    *(float4*)&Pr[s2][4] = *(const float4*)(p + 4);
  }

  // ---- phase A: per-(point,level) params (96 tasks) ----
  if (t < 96) {
    const int pt = t & 31, lv = t >> 5;
    const int gpt = row0 + pt;
    const int b = (gpt >= NPTS) ? 1 : 0;
    const float* P = pts + (size_t)gpt * 3;
    const float* T = trans + b * 3;
    const float* R = rot + b * 9;
    const float* L = l2i + b * 16;
    float dx = P[0] - T[0], dy = P[1] - T[1], dz = P[2] - T[2];
    float p0 = dx * R[0] + dy * R[1] + dz * R[2];
    float p1 = dx * R[3] + dy * R[4] + dz * R[5];
    float p2 = dx * R[6] + dy * R[7] + dz * R[8];
    float pc0 = L[0] * p0 + L[1] * p1 + L[2]  * p2 + L[3];
    float pc1 = L[4] * p0 + L[5] * p1 + L[6]  * p2 + L[7];
    float pc2 = L[8] * p0 + L[9] * p1 + L[10] * p2 + L[11];
    float z  = fmaxf(pc2, 1e-5f);
    float gx = pc0 / z / WPADf * 2.f - 1.f;
    float gy = pc1 / z / HPADf * 2.f - 1.f;

    const int Wl = 160 >> lv, Hl = 48 >> lv;
    const float Wm1 = (float)(Wl - 1), Hm1 = (float)(Hl - 1);
    float ix = (gx + 1.f) * 0.5f * Wm1;
    float iy = (gy + 1.f) * 0.5f * Hm1;
    float xf = floorf(ix), yf = floorf(iy);
    float wx1 = ix - xf, wy1 = iy - yf;
    float wx0 = 1.f - wx1, wy0 = 1.f - wy1;
    float ax0 = (xf >= 0.f       && xf <= Wm1)       ? wx0 : 0.f;
    float ax1 = (xf + 1.f >= 0.f && xf + 1.f <= Wm1) ? wx1 : 0.f;
    float ay0 = (yf >= 0.f       && yf <= Hm1)       ? wy0 : 0.f;
    float ay1 = (yf + 1.f >= 0.f && yf + 1.f <= Hm1) ? wy1 : 0.f;
    int xi0 = (int)fminf(fmaxf(xf,       0.f), Wm1);
    int xi1 = (int)fminf(fmaxf(xf + 1.f, 0.f), Wm1);
    int yi0 = (int)fminf(fmaxf(yf,       0.f), Hm1);
    int yi1 = (int)fminf(fmaxf(yf + 1.f, 0.f), Hm1);

    const int foff = (lv == 0) ? 0 : (lv == 1) ? 1966080 : 2457600;  // elems
    const int base = (foff + ((b * Hl + yi0) * Wl + xi0) * MIDC) * 2;
    const int dxB  = (xi1 - xi0) * MIDC * 2;
    const int dyB  = (yi1 - yi0) * Wl * MIDC * 2;

    float* pp = sP + (lv * 32 + pt) * 8;
    pp[0] = ax0 * ay0; pp[1] = ax1 * ay0; pp[2] = ax0 * ay1; pp[3] = ax1 * ay1;
    ((int*)pp)[4] = base; ((int*)pp)[5] = dxB; ((int*)pp)[6] = dyB;
  }
  __syncthreads();

  // ---- phase B: gather, 16 lanes/point, 8 ch/lane ----
  {
    const int lane = t & 15, g = t >> 4;
    #pragma unroll
    for (int it = 0; it < 6; ++it) {
      const int lv = it >> 1;                 // uniform per iteration
      const int pt = (it & 1) * 16 + g;
      const float* __restrict__ pp = sP + (lv * 32 + pt) * 8;
      const float4 w = *(const float4*)pp;
      const int base = ((const int*)pp)[4];
      const int dxB  = ((const int*)pp)[5];
      const int dyB  = ((const int*)pp)[6];
      const char* __restrict__ src = (const char*)cbuf + base + lane * 16;
      uint4 q00 = *(const uint4*)(src);
      uint4 q10 = *(const uint4*)(src + dxB);
      uint4 q01 = *(const uint4*)(src + dyB);
      uint4 q11 = *(const uint4*)(src + dxB + dyB);
      const unsigned* a00 = (const unsigned*)&q00;
      const unsigned* a10 = (const unsigned*)&q10;
      const unsigned* a01 = (const unsigned*)&q01;
      const unsigned* a11 = (const unsigned*)&q11;
      uint4 o;
      unsigned* op = (unsigned*)&o;
      #pragma unroll
      for (int j = 0; j < 4; ++j) {
        float rl = blo(a00[j]) * w.x + blo(a10[j]) * w.y
                 + blo(a01[j]) * w.z + blo(a11[j]) * w.w;
        float rh = bhi(a00[j]) * w.x + bhi(a10[j]) * w.y
                 + bhi(a01[j]) * w.z + bhi(a11[j]) * w.w;
        op[j] = (unsigned)f2bf(rl) | ((unsigned)f2bf(rh) << 16);
      }
      const int slot = (lv * 16 + lane) ^ (pt & 7);
      *(uint4*)((char*)sA + pt * 768 + slot * 16) = o;
    }
  }
  __syncthreads();

  // ---- phase 2: GEMM (M=32) from LDS A + reg B ----
  f32x4 acc[4] = {};
  bf16x8 Ab[2];
  const int arow = rg * 16 + lr;
  auto loadA = [&](int ks) {
    const int slot = (ks * 4 + lk) ^ (arow & 7);
    Ab[ks & 1] = *(const bf16x8*)((const char*)sA + arow * 768 + slot * 16);
  };
  loadA(0);

  #pragma unroll
  for (int ks = 0; ks < 14; ++ks) {
    if (ks + 1 < 12) loadA(ks + 1);
    bf16x8 A0;
    if (ks < 12) {
      A0 = Ab[ks & 1];
    } else {
      #pragma unroll
      for (int j = 0; j < 8; ++j) A0[j] = (short)f2bf(Pr[ks - 12][j]);
    }
    acc[0] = __builtin_amdgcn_mfma_f32_16x16x32_bf16(A0, Br[ks & 3][0], acc[0], 0, 0, 0);
    acc[1] = __builtin_amdgcn_mfma_f32_16x16x32_bf16(A0, Br[ks & 3][1], acc[1], 0, 0, 0);
    acc[2] = __builtin_amdgcn_mfma_f32_16x16x32_bf16(A0, Br[ks & 3][2], acc[2], 0, 0, 0);
    acc[3] = __builtin_amdgcn_mfma_f32_16x16x32_bf16(A0, Br[ks & 3][3], acc[3], 0, 0, 0);
    if (ks + 4 < 14) loadB(ks + 4);
  }

  #pragma unroll
  for (int rr = 0; rr < 4; ++rr) {
    const int row = row0 + rg * 16 + lk * 4 + rr;
    float* __restrict__ po = outp + (size_t)row * OUTC;
    #pragma unroll
    for (int nf = 0; nf < 4; ++nf) {
      const int col = wn * 64 + nf * 16 + lr;
      po[col] = fmaxf(acc[nf][rr] + bias[col], 0.f);
    }
  }
}

// ================================= host ====================================
extern "C" void kernel_launch(void* const* d_in, const int* in_sizes, int n_in,
                              void* d_out, int out_size, void* d_ws, size_t ws_size,
                              hipStream_t stream) {
  const float* f0_in  = (const float*)d_in[0];
  const float* f1_in  = (const float*)d_in[1];
  const float* f2_in  = (const float*)d_in[2];
  const float* pts    = (const float*)d_in[3];
  const float* ptsf   = (const float*)d_in[4];
  const float* l2i    = (const float*)d_in[5];
  const float* rot    = (const float*)d_in[6];
  const float* trans  = (const float*)d_in[7];
  const float* lat_w  = (const float*)d_in[8];
  const float* lat_b  = (const float*)d_in[9];
  const float* img_w  = (const float*)d_in[10];
  const float* img_b  = (const float*)d_in[11];
  const float* pts_w  = (const float*)d_in[12];
  const float* pts_b  = (const float*)d_in[13];
  const float* ibg    = (const float*)d_in[14];
  const float* ibbv   = (const float*)d_in[15];
  const float* ibm    = (const float*)d_in[16];
  const float* ibv    = (const float*)d_in[17];
  const float* pbg    = (const float*)d_in[18];
  const float* pbbv   = (const float*)d_in[19];
  const float* pbm    = (const float*)d_in[20];
  const float* pbv    = (const float*)d_in[21];
  float* outp = (float*)d_out;

  uint8_t* ws = (uint8_t*)d_ws;
  const size_t off_wc   = 0;                        // 3*294912 bf16
  const size_t off_wg   = 1769472;                  // 57344 bf16
  const size_t off_bias = 1884160;                  // 128 f32
  const size_t off_c0   = 1884672;
  const size_t off_c1   = off_c0 + 3932160;
  const size_t off_c2   = off_c1 + 983040;
  const size_t off_big  = off_c2 + 245760;          // padded conv inputs
  const size_t p0_off = 0;
  const size_t p1_off = 4147200;
  const size_t p2_off = 5238784;

  u16*   wc   = (u16*)(ws + off_wc);
  u16*   wg   = (u16*)(ws + off_wg);
  float* bias = (float*)(ws + off_bias);
  u16*   c0   = (u16*)(ws + off_c0);
  u16*   big  = (u16*)(ws + off_big);

  // 1) zero padded region (+16 KB slack for edge-tile overreads)
  zero_kernel<<<1024, 256, 0, stream>>>((uint4*)big, (5539840 * 2 + 16384) / 16);

  // 2) NCHW f32 -> padded NHWC bf16
  nchw2nhwc_kernel<<<dim3(5, 48, 8), 256, 0, stream>>>(f0_in, big + p0_off, 48, 160);
  nchw2nhwc_kernel<<<dim3(3, 24, 8), 256, 0, stream>>>(f1_in, big + p1_off, 24, 80);
  nchw2nhwc_kernel<<<dim3(2, 12, 8), 256, 0, stream>>>(f2_in, big + p2_off, 12, 40);

  // 3) weight prep
  prep_kernel<<<3680, 256, 0, stream>>>(
      img_w, img_b, pts_w, pts_b, ibg, ibbv, ibm, ibv,
      pbg, pbbv, pbm, pbv, lat_w, wg, wc, bias);

  // 4) conv, all levels in one dispatch (writes c0/c1/c2 region from base c0)
  ConvParams P;
  P.base[0] = 0; P.base[1] = 240; P.base[2] = 300; P.base[3] = 318;
  P.H[0] = 48;  P.H[1] = 24; P.H[2] = 12;
  P.W[0] = 160; P.W[1] = 80; P.W[2] = 40;
  P.tx[0] = 10; P.tx[1] = 5;  P.tx[2] = 3;
  P.poff[0] = (int)p0_off; P.poff[1] = (int)p1_off; P.poff[2] = (int)p2_off;
  P.coff[0] = 0; P.coff[1] = 1966080; P.coff[2] = 2457600;
  P.woff[0] = 0; P.woff[1] = 294912;  P.woff[2] = 589824;
  conv_mfma_kernel<<<318, 256, 0, stream>>>(big, wc, lat_b, c0, P);

  // 5) fused sample + GEMM + bias + BN + relu  (M=32 tiles; 100000/32 = 3125)
  sample_gemm_kernel<<<TOTPTS / 32, 256, 0, stream>>>(
      pts, l2i, rot, trans, c0, ptsf, wg, bias, outp);

  (void)in_sizes; (void)n_in; (void)out_size; (void)ws_size;
}